// Round 8
// baseline (299.619 us; speedup 1.0000x reference)
//
#include <hip/hip_runtime.h>

#define N_V 35709
#define N_F 70789
#define NR  (3*N_V)   // 107127
#define NB  64

// ws layout (floats), fast path:
//   rotM  : NB*9   = 576    @ 0
//   gm    : NB*27  = 1728   @ 576
//   ctrS  : 144*NB = 9216   @ 2304   (id+ex coeffs, [j][b])
//   ctrT  : 80*NB  = 5120   @ 11520  (tex coeffs, [j][b])
//   shape3: N_V*64*3       @ 16640   (pre-rotation shape, [(v*64+b)*3+c])
//   tex3  : N_V*64*3       @ +sh3    (texture/255, same layout)
//   fnT3  : (N_F+1)*64*3   @ +sh3    (unit face normals, sentinel 0 at f=N_F)
// Fallback path (small ws) reuses 16640.. as shapeT[i][64] / texT[i][64].
#define WS_ROT    0
#define WS_GM     576
#define WS_CTRS   2304
#define WS_CTRT   11520
#define WS_MAIN   16640

__global__ __launch_bounds__(64) void k_setup_rot(
    const float* __restrict__ coeffs, const float* __restrict__ init_lit,
    float* __restrict__ rotM, float* __restrict__ gm)
{
    int b = threadIdx.x;
    const float* cb = coeffs + b * 257;

    float ax = cb[224], ay = cb[225], az = cb[226];
    float cx = cosf(ax), sx = sinf(ax);
    float cy = cosf(ay), sy = sinf(ay);
    float cz = cosf(az), sz = sinf(az);
    float m[9];
    m[0] = cz * cy;
    m[1] = cz * sy * sx - sz * cx;
    m[2] = sz * sx + cz * sy * cx;
    m[3] = sz * cy;
    m[4] = cz * cx + sz * sy * sx;
    m[5] = sz * sy * cx - cz * sx;
    m[6] = -sy;
    m[7] = cy * sx;
    m[8] = cy * cx;
#pragma unroll
    for (int k = 0; k < 9; k++) rotM[b * 9 + k] = m[k];

#pragma unroll
    for (int k = 0; k < 9; k++) {
        float il = init_lit[k];
#pragma unroll
        for (int c = 0; c < 3; c++)
            gm[b * 27 + k * 3 + c] = cb[227 + c * 9 + k] + il;
    }
}

// grid = 224 blocks of 64: block j transposes coeff column j into [j][b]
__global__ __launch_bounds__(64) void k_transpose(
    const float* __restrict__ coeffs,
    float* __restrict__ ctrS, float* __restrict__ ctrT)
{
    int j = blockIdx.x;
    int b = threadIdx.x;
    float v = coeffs[b * 257 + j];
    if (j < 144) ctrS[j * 64 + b] = v;
    else         ctrT[(j - 144) * 64 + b] = v;
}

// Shape GEMM (round-7 verified tile structure), writing shape3 layout directly.
// Block: 256 threads -> 64-row x 64-batch tile; per-thread 4 rows x 4 batches.
__global__ __launch_bounds__(256) void k_gemm_shape3(
    const float* __restrict__ idBase, const float* __restrict__ exBase,
    const float* __restrict__ meanshape,
    const float* __restrict__ ctrS,
    float* __restrict__ shape3)
{
    __shared__ __align__(16) float As[16][68];
    __shared__ __align__(16) float Bs[16][64];

    const int t  = threadIdx.x;
    const int tn = t & 15;
    const int tm = t >> 4;
    const int r0 = blockIdx.x * 64;

    const int srow = t >> 2;
    const int sc   = t & 3;
    int srg = r0 + srow; if (srg > NR - 1) srg = NR - 1;

    float acc[4][4];
#pragma unroll
    for (int i = 0; i < 4; i++)
#pragma unroll
        for (int j = 0; j < 4; j++) acc[i][j] = 0.f;

    for (int kc = 0; kc < 9; kc++) {
        const float* src;
        int ld, k0;
        if (kc < 5) { src = idBase; ld = 80; k0 = kc * 16; }
        else        { src = exBase; ld = 64; k0 = (kc - 5) * 16; }

        {
            float4 v = *(const float4*)(src + (size_t)srg * ld + k0 + sc * 4);
            As[sc * 4 + 0][srow] = v.x;
            As[sc * 4 + 1][srow] = v.y;
            As[sc * 4 + 2][srow] = v.z;
            As[sc * 4 + 3][srow] = v.w;
        }
        ((float4*)&Bs[0][0])[t] = ((const float4*)(ctrS + (size_t)kc * 16 * 64))[t];
        __syncthreads();

#pragma unroll
        for (int k = 0; k < 16; k++) {
            float4 a = *(const float4*)&As[k][tm * 4];
            float4 b = *(const float4*)&Bs[k][tn * 4];
            float av[4] = {a.x, a.y, a.z, a.w};
            float bv[4] = {b.x, b.y, b.z, b.w};
#pragma unroll
            for (int i = 0; i < 4; i++)
#pragma unroll
                for (int j = 0; j < 4; j++)
                    acc[i][j] += av[i] * bv[j];
        }
        __syncthreads();
    }

    // epilogue: scatter into shape3[(v*64+b)*3 + c]; one row's wave-stores span
    // a contiguous 768-B region (streaming writes).
#pragma unroll
    for (int i = 0; i < 4; i++) {
        int r = r0 + tm * 4 + i;
        if (r < NR) {
            float ms = meanshape[r];
            int v = r / 3;
            int c = r - v * 3;
            float* o = shape3 + ((size_t)v * 64 + tn * 4) * 3 + c;
            o[0] = acc[i][0] + ms;
            o[3] = acc[i][1] + ms;
            o[6] = acc[i][2] + ms;
            o[9] = acc[i][3] + ms;
        }
    }
}

// Hybrid kernel: interleaved block roles.
//   tex-GEMM blocks (GB = ceil(NR/64)): VALU-bound, write tex3.
//   facenorm blocks (FB = ceil((N_F+1)/32)): memory-bound gathers from shape3,
//   write fnT3 (sentinel zero at f==N_F).
// Mapping (requires FB >= GB): x<2*GB: even->tex(x/2), odd->fn(x/2);
// x>=2*GB: fn(x-GB). Complementary pipes share CUs.
__global__ __launch_bounds__(256) void k_fn_texgemm(
    const float* __restrict__ texBase, const float* __restrict__ meantex,
    const float* __restrict__ ctrT,
    const float* __restrict__ shape3, const int* __restrict__ face_buf,
    float* __restrict__ tex3, float* __restrict__ fnT3, int GB)
{
    __shared__ __align__(16) float As[16][68];
    __shared__ __align__(16) float Bs[16][64];

    int x = blockIdx.x;
    int role_tex, idx;
    if (x < 2 * GB) { role_tex = ((x & 1) == 0); idx = x >> 1; }
    else            { role_tex = 0; idx = x - GB; }

    if (role_tex) {
        const int t  = threadIdx.x;
        const int tn = t & 15;
        const int tm = t >> 4;
        const int r0 = idx * 64;
        const int srow = t >> 2;
        const int sc   = t & 3;
        int srg = r0 + srow; if (srg > NR - 1) srg = NR - 1;

        float acc[4][4];
#pragma unroll
        for (int i = 0; i < 4; i++)
#pragma unroll
            for (int j = 0; j < 4; j++) acc[i][j] = 0.f;

        for (int kc = 0; kc < 5; kc++) {
            int k0 = kc * 16;
            {
                float4 v = *(const float4*)(texBase + (size_t)srg * 80 + k0 + sc * 4);
                As[sc * 4 + 0][srow] = v.x;
                As[sc * 4 + 1][srow] = v.y;
                As[sc * 4 + 2][srow] = v.z;
                As[sc * 4 + 3][srow] = v.w;
            }
            ((float4*)&Bs[0][0])[t] = ((const float4*)(ctrT + (size_t)kc * 16 * 64))[t];
            __syncthreads();

#pragma unroll
            for (int k = 0; k < 16; k++) {
                float4 a = *(const float4*)&As[k][tm * 4];
                float4 b = *(const float4*)&Bs[k][tn * 4];
                float av[4] = {a.x, a.y, a.z, a.w};
                float bv[4] = {b.x, b.y, b.z, b.w};
#pragma unroll
                for (int i = 0; i < 4; i++)
#pragma unroll
                    for (int j = 0; j < 4; j++)
                        acc[i][j] += av[i] * bv[j];
            }
            __syncthreads();
        }

        const float inv255 = 1.0f / 255.0f;
#pragma unroll
        for (int i = 0; i < 4; i++) {
            int r = r0 + tm * 4 + i;
            if (r < NR) {
                float mt = meantex[r];
                int v = r / 3;
                int c = r - v * 3;
                float* o = tex3 + ((size_t)v * 64 + tn * 4) * 3 + c;
                o[0] = (acc[i][0] + mt) * inv255;
                o[3] = (acc[i][1] + mt) * inv255;
                o[6] = (acc[i][2] + mt) * inv255;
                o[9] = (acc[i][3] + mt) * inv255;
            }
        }
    } else {
        int wave = threadIdx.x >> 6;
        int b    = threadIdx.x & 63;
        int f0   = idx * 32 + wave * 8;
#pragma unroll
        for (int fr = 0; fr < 8; fr++) {
            int f = f0 + fr;
            if (f < N_F) {
                int i0 = face_buf[f * 3 + 0];
                int i1 = face_buf[f * 3 + 1];
                int i2 = face_buf[f * 3 + 2];
                const float* p0 = shape3 + ((size_t)i0 * 64 + b) * 3;
                const float* p1 = shape3 + ((size_t)i1 * 64 + b) * 3;
                const float* p2 = shape3 + ((size_t)i2 * 64 + b) * 3;
                float p0x = p0[0], p0y = p0[1], p0z = p0[2];
                float p1x = p1[0], p1y = p1[1], p1z = p1[2];
                float p2x = p2[0], p2y = p2[1], p2z = p2[2];
                float e1x = p0x - p1x, e1y = p0y - p1y, e1z = p0z - p1z;
                float e2x = p1x - p2x, e2y = p1y - p2y, e2z = p1z - p2z;
                float ccx = e1y * e2z - e1z * e2y;
                float ccy = e1z * e2x - e1x * e2z;
                float ccz = e1x * e2y - e1y * e2x;
                float l = sqrtf(ccx * ccx + ccy * ccy + ccz * ccz);
                float inv = 1.0f / fmaxf(l, 1e-12f);
                float* o = fnT3 + ((size_t)f * 64 + b) * 3;
                o[0] = ccx * inv; o[1] = ccy * inv; o[2] = ccz * inv;
            } else if (f == N_F) {
                float* o = fnT3 + ((size_t)f * 64 + b) * 3;
                o[0] = 0.f; o[1] = 0.f; o[2] = 0.f;
            }
        }
    }
}

// Vertex kernel + fused landmark tail blocks.
// Blocks [0,VB): 16 vertices x 64 batches (wave=4 vertices, lane=batch).
// Blocks [VB, VB+17): landmark; wave handles landmark l=(x-VB)*4+wave.
__global__ __launch_bounds__(256) void k_vertex_lm(
    const float* __restrict__ shape3,  // [(v*64+b)*3+c]
    const float* __restrict__ tex3,
    const float* __restrict__ fnT3,
    const float* __restrict__ rotM, const float* __restrict__ gm,
    const float* __restrict__ coeffs,
    const int* __restrict__ point_buf, const int* __restrict__ keypoints,
    const float* __restrict__ P,
    float* __restrict__ out_vertex, float* __restrict__ out_color,
    float* __restrict__ out_lm, int VB)
{
    __shared__ float sh[64 * 49];   // [b][48] padded to 49
    int x    = blockIdx.x;
    int wave = threadIdx.x >> 6;
    int b    = threadIdx.x & 63;

    float m0 = rotM[b * 9 + 0], m1 = rotM[b * 9 + 1], m2 = rotM[b * 9 + 2];
    float m3 = rotM[b * 9 + 3], m4 = rotM[b * 9 + 4], m5 = rotM[b * 9 + 5];
    float m6 = rotM[b * 9 + 6], m7 = rotM[b * 9 + 7], m8 = rotM[b * 9 + 8];
    float tx = coeffs[b * 257 + 254], ty = coeffs[b * 257 + 255], tz = coeffs[b * 257 + 256];

    if (x >= VB) {
        // ---- landmark role ----
        int l = (x - VB) * 4 + wave;
        if (l < 68) {
            int kp = keypoints[l];
            const float* sp = shape3 + ((size_t)kp * 64 + b) * 3;
            float sx0 = sp[0], sy0 = sp[1], sz0 = sp[2];
            float xx = m0 * sx0 + m1 * sy0 + m2 * sz0 + tx;
            float yy = m3 * sx0 + m4 * sy0 + m5 * sz0 + ty;
            float zz = 10.0f - (m6 * sx0 + m7 * sy0 + m8 * sz0 + tz);
            float p0 = xx * P[0] + yy * P[3] + zz * P[6];
            float p1 = xx * P[1] + yy * P[4] + zz * P[7];
            float p2 = xx * P[2] + yy * P[5] + zz * P[8];
            size_t o = ((size_t)b * 68 + l) * 2;
            out_lm[o]     = p0 / p2;
            out_lm[o + 1] = p1 / p2;
        }
        return;
    }

    int v0 = x * 16;
    int nvalid = N_V - v0; if (nvalid > 16) nvalid = 16;
    int kmax = 3 * nvalid;

    float g[27];
#pragma unroll
    for (int k = 0; k < 27; k++) g[k] = gm[b * 27 + k];

    const float A0C0 = 0.8862269254527580f;
    const float A1C1 = 1.7724538509055159f;
    const float A2C2 = 2.4270323912f;
    const float C6   = 0.7006239022f;
    const float C8   = 1.2135161956f;

    // ---- hoisted loads ----
    int pf[4][8];
    float sxv[4], syv[4], szv[4];
    float t0v[4], t1v[4], t2v[4];
#pragma unroll
    for (int vr = 0; vr < 4; vr++) {
        int v = v0 + wave * 4 + vr;
        int vc = (v < N_V) ? v : (N_V - 1);
#pragma unroll
        for (int k = 0; k < 8; k++) pf[vr][k] = point_buf[vc * 8 + k];
        const float* sp = shape3 + ((size_t)vc * 64 + b) * 3;
        sxv[vr] = sp[0]; syv[vr] = sp[1]; szv[vr] = sp[2];
        const float* tp = tex3 + ((size_t)vc * 64 + b) * 3;
        t0v[vr] = tp[0]; t1v[vr] = tp[1]; t2v[vr] = tp[2];
    }

    float vert[4][3];
    float col[4][3];

#pragma unroll
    for (int vr = 0; vr < 4; vr++) {
        float fx[8], fy[8], fz[8];
#pragma unroll
        for (int k = 0; k < 8; k++) {
            const float* fp = fnT3 + ((size_t)pf[vr][k] * 64 + b) * 3;
            fx[k] = fp[0]; fy[k] = fp[1]; fz[k] = fp[2];
        }

        float vx = m0 * sxv[vr] + m1 * syv[vr] + m2 * szv[vr] + tx;
        float vy = m3 * sxv[vr] + m4 * syv[vr] + m5 * szv[vr] + ty;
        float vz = m6 * sxv[vr] + m7 * syv[vr] + m8 * szv[vr] + tz;
        vert[vr][0] = vx; vert[vr][1] = vy; vert[vr][2] = 10.0f - vz;

        float nx = 0.f, ny = 0.f, nz = 0.f;
#pragma unroll
        for (int k = 0; k < 8; k++) { nx += fx[k]; ny += fy[k]; nz += fz[k]; }
        float l = sqrtf(nx * nx + ny * ny + nz * nz);
        float inv = 1.0f / fmaxf(l, 1e-12f);
        nx *= inv; ny *= inv; nz *= inv;

        float rx = m0 * nx + m1 * ny + m2 * nz;
        float ry = m3 * nx + m4 * ny + m5 * nz;
        float rz = m6 * nx + m7 * ny + m8 * nz;

        float Y0 = A0C0;
        float Y1 = -A1C1 * ry;
        float Y2 =  A1C1 * rz;
        float Y3 = -A1C1 * rx;
        float Y4 =  A2C2 * rx * ry;
        float Y5 = -A2C2 * ry * rz;
        float Y6 =  C6 * (3.f * rz * rz - 1.f);
        float Y7 = -A2C2 * rx * rz;
        float Y8 =  C8 * (rx * rx - ry * ry);

        float tex3v[3] = {t0v[vr], t1v[vr], t2v[vr]};
#pragma unroll
        for (int c = 0; c < 3; c++) {
            float rgb = Y0 * g[0 + c] + Y1 * g[3 + c] + Y2 * g[6 + c] + Y3 * g[9 + c] +
                        Y4 * g[12 + c] + Y5 * g[15 + c] + Y6 * g[18 + c] + Y7 * g[21 + c] +
                        Y8 * g[24 + c];
            col[vr][c] = rgb * tex3v[c];
        }
    }

    // ---- stage + flush vertex ----
#pragma unroll
    for (int vr = 0; vr < 4; vr++)
#pragma unroll
        for (int c = 0; c < 3; c++)
            sh[b * 49 + (wave * 4 + vr) * 3 + c] = vert[vr][c];
    __syncthreads();
#pragma unroll 4
    for (int it = 0; it < 12; it++) {
        int f = it * 256 + threadIdx.x;
        int bb = f / 48, k = f - bb * 48;
        if (k < kmax)
            __builtin_nontemporal_store(sh[bb * 49 + k],
                                        out_vertex + (size_t)bb * NR + 3 * (size_t)v0 + k);
    }
    __syncthreads();

    // ---- stage + flush color ----
#pragma unroll
    for (int vr = 0; vr < 4; vr++)
#pragma unroll
        for (int c = 0; c < 3; c++)
            sh[b * 49 + (wave * 4 + vr) * 3 + c] = col[vr][c];
    __syncthreads();
#pragma unroll 4
    for (int it = 0; it < 12; it++) {
        int f = it * 256 + threadIdx.x;
        int bb = f / 48, k = f - bb * 48;
        if (k < kmax)
            __builtin_nontemporal_store(sh[bb * 49 + k],
                                        out_color + (size_t)bb * NR + 3 * (size_t)v0 + k);
    }
}

// ================= FALLBACK PATH (small ws): round-7 verified kernels =================

__global__ __launch_bounds__(256) void k_gemm_tile(
    const float* __restrict__ idBase, const float* __restrict__ exBase,
    const float* __restrict__ texBase, const float* __restrict__ meanshape,
    const float* __restrict__ meantex,
    const float* __restrict__ ctrS, const float* __restrict__ ctrT,
    float* __restrict__ shapeT,      // ws, [i][64]
    float* __restrict__ texT,        // [i][64] if transposed, else out_color [b][NR]
    int tex_transposed)
{
    __shared__ __align__(16) float As[16][68];
    __shared__ __align__(16) float Bs[16][64];

    const int t  = threadIdx.x;
    const int tn = t & 15;
    const int tm = t >> 4;
    const int r0 = blockIdx.x * 64;

    const int srow = t >> 2;
    const int sc   = t & 3;
    int srg = r0 + srow; if (srg > NR - 1) srg = NR - 1;

    float acc[4][4];
#pragma unroll
    for (int i = 0; i < 4; i++)
#pragma unroll
        for (int j = 0; j < 4; j++) acc[i][j] = 0.f;

    for (int kc = 0; kc < 9; kc++) {
        const float* src;
        int ld, k0;
        if (kc < 5) { src = idBase; ld = 80; k0 = kc * 16; }
        else        { src = exBase; ld = 64; k0 = (kc - 5) * 16; }
        {
            float4 v = *(const float4*)(src + (size_t)srg * ld + k0 + sc * 4);
            As[sc * 4 + 0][srow] = v.x;
            As[sc * 4 + 1][srow] = v.y;
            As[sc * 4 + 2][srow] = v.z;
            As[sc * 4 + 3][srow] = v.w;
        }
        ((float4*)&Bs[0][0])[t] = ((const float4*)(ctrS + (size_t)kc * 16 * 64))[t];
        __syncthreads();
#pragma unroll
        for (int k = 0; k < 16; k++) {
            float4 a = *(const float4*)&As[k][tm * 4];
            float4 b = *(const float4*)&Bs[k][tn * 4];
            float av[4] = {a.x, a.y, a.z, a.w};
            float bv[4] = {b.x, b.y, b.z, b.w};
#pragma unroll
            for (int i = 0; i < 4; i++)
#pragma unroll
                for (int j = 0; j < 4; j++)
                    acc[i][j] += av[i] * bv[j];
        }
        __syncthreads();
    }

#pragma unroll
    for (int i = 0; i < 4; i++) {
        int rg = r0 + tm * 4 + i;
        if (rg < NR) {
            float ms = meanshape[rg];
            float4 o = {acc[i][0] + ms, acc[i][1] + ms, acc[i][2] + ms, acc[i][3] + ms};
            *(float4*)(shapeT + (size_t)rg * 64 + tn * 4) = o;
        }
    }

#pragma unroll
    for (int i = 0; i < 4; i++)
#pragma unroll
        for (int j = 0; j < 4; j++) acc[i][j] = 0.f;

    for (int kc = 0; kc < 5; kc++) {
        int k0 = kc * 16;
        {
            float4 v = *(const float4*)(texBase + (size_t)srg * 80 + k0 + sc * 4);
            As[sc * 4 + 0][srow] = v.x;
            As[sc * 4 + 1][srow] = v.y;
            As[sc * 4 + 2][srow] = v.z;
            As[sc * 4 + 3][srow] = v.w;
        }
        ((float4*)&Bs[0][0])[t] = ((const float4*)(ctrT + (size_t)kc * 16 * 64))[t];
        __syncthreads();
#pragma unroll
        for (int k = 0; k < 16; k++) {
            float4 a = *(const float4*)&As[k][tm * 4];
            float4 b = *(const float4*)&Bs[k][tn * 4];
            float av[4] = {a.x, a.y, a.z, a.w};
            float bv[4] = {b.x, b.y, b.z, b.w};
#pragma unroll
            for (int i = 0; i < 4; i++)
#pragma unroll
                for (int j = 0; j < 4; j++)
                    acc[i][j] += av[i] * bv[j];
        }
        __syncthreads();
    }

    const float inv255 = 1.0f / 255.0f;
    if (tex_transposed) {
#pragma unroll
        for (int i = 0; i < 4; i++) {
            int rg = r0 + tm * 4 + i;
            if (rg < NR) {
                float mt = meantex[rg];
                float4 o = {(acc[i][0] + mt) * inv255, (acc[i][1] + mt) * inv255,
                            (acc[i][2] + mt) * inv255, (acc[i][3] + mt) * inv255};
                *(float4*)(texT + (size_t)rg * 64 + tn * 4) = o;
            }
        }
    } else {
#pragma unroll
        for (int i = 0; i < 4; i++) {
            int rg = r0 + tm * 4 + i;
            if (rg < NR) {
                float mt = meantex[rg];
#pragma unroll
                for (int j = 0; j < 4; j++)
                    texT[(size_t)(tn * 4 + j) * NR + rg] = (acc[i][j] + mt) * inv255;
            }
        }
    }
}

__global__ __launch_bounds__(256) void k_vertex(
    const float* __restrict__ shapeT,
    const float* __restrict__ texT,
    const float* __restrict__ rotM, const float* __restrict__ gm,
    const float* __restrict__ coeffs,
    const int* __restrict__ point_buf, const int* __restrict__ face_buf,
    float* __restrict__ out_vertex, float* __restrict__ out_color,
    int tex_in_out)
{
    __shared__ float sh[64 * 97];
    int wave = threadIdx.x >> 6;
    int b    = threadIdx.x & 63;
    int v0   = blockIdx.x * 32;
    int nvalid = N_V - v0; if (nvalid > 32) nvalid = 32;
    int kmax = 3 * nvalid;

    float m0 = rotM[b * 9 + 0], m1 = rotM[b * 9 + 1], m2 = rotM[b * 9 + 2];
    float m3 = rotM[b * 9 + 3], m4 = rotM[b * 9 + 4], m5 = rotM[b * 9 + 5];
    float m6 = rotM[b * 9 + 6], m7 = rotM[b * 9 + 7], m8 = rotM[b * 9 + 8];
    float tx = coeffs[b * 257 + 254], ty = coeffs[b * 257 + 255], tz = coeffs[b * 257 + 256];
    float g[27];
#pragma unroll
    for (int k = 0; k < 27; k++) g[k] = gm[b * 27 + k];

    const float A0C0 = 0.8862269254527580f;
    const float A1C1 = 1.7724538509055159f;
    const float A2C2 = 2.4270323912f;
    const float C6   = 0.7006239022f;
    const float C8   = 1.2135161956f;

    float vert[8][3];
    float col[8][3];

#pragma unroll
    for (int vr = 0; vr < 8; vr++) {
        int v = v0 + wave * 8 + vr;
        bool valid = (v < N_V);
        int vc = valid ? v : (N_V - 1);

        float sx0 = shapeT[(size_t)(3 * vc)     * 64 + b];
        float sy0 = shapeT[(size_t)(3 * vc + 1) * 64 + b];
        float sz0 = shapeT[(size_t)(3 * vc + 2) * 64 + b];

        float vx = m0 * sx0 + m1 * sy0 + m2 * sz0 + tx;
        float vy = m3 * sx0 + m4 * sy0 + m5 * sz0 + ty;
        float vz = m6 * sx0 + m7 * sy0 + m8 * sz0 + tz;
        vert[vr][0] = vx; vert[vr][1] = vy; vert[vr][2] = 10.0f - vz;

        float nx = 0.f, ny = 0.f, nz = 0.f;
#pragma unroll
        for (int k = 0; k < 8; k++) {
            int f = point_buf[vc * 8 + k];
            if (f < N_F) {
                int i0 = face_buf[f * 3], i1 = face_buf[f * 3 + 1], i2 = face_buf[f * 3 + 2];
                float p0x = shapeT[(size_t)(3 * i0)     * 64 + b];
                float p0y = shapeT[(size_t)(3 * i0 + 1) * 64 + b];
                float p0z = shapeT[(size_t)(3 * i0 + 2) * 64 + b];
                float p1x = shapeT[(size_t)(3 * i1)     * 64 + b];
                float p1y = shapeT[(size_t)(3 * i1 + 1) * 64 + b];
                float p1z = shapeT[(size_t)(3 * i1 + 2) * 64 + b];
                float p2x = shapeT[(size_t)(3 * i2)     * 64 + b];
                float p2y = shapeT[(size_t)(3 * i2 + 1) * 64 + b];
                float p2z = shapeT[(size_t)(3 * i2 + 2) * 64 + b];
                float e1x = p0x - p1x, e1y = p0y - p1y, e1z = p0z - p1z;
                float e2x = p1x - p2x, e2y = p1y - p2y, e2z = p1z - p2z;
                float ccx = e1y * e2z - e1z * e2y;
                float ccy = e1z * e2x - e1x * e2z;
                float ccz = e1x * e2y - e1y * e2x;
                float l = sqrtf(ccx * ccx + ccy * ccy + ccz * ccz);
                float inv = 1.0f / fmaxf(l, 1e-12f);
                nx += ccx * inv; ny += ccy * inv; nz += ccz * inv;
            }
        }
        float l = sqrtf(nx * nx + ny * ny + nz * nz);
        float inv = 1.0f / fmaxf(l, 1e-12f);
        nx *= inv; ny *= inv; nz *= inv;

        float rx = m0 * nx + m1 * ny + m2 * nz;
        float ry = m3 * nx + m4 * ny + m5 * nz;
        float rz = m6 * nx + m7 * ny + m8 * nz;

        float Y0 = A0C0;
        float Y1 = -A1C1 * ry;
        float Y2 =  A1C1 * rz;
        float Y3 = -A1C1 * rx;
        float Y4 =  A2C2 * rx * ry;
        float Y5 = -A2C2 * ry * rz;
        float Y6 =  C6 * (3.f * rz * rz - 1.f);
        float Y7 = -A2C2 * rx * rz;
        float Y8 =  C8 * (rx * rx - ry * ry);

        float t0, t1, t2;
        if (tex_in_out) {
            size_t ob = (size_t)b * NR + 3 * (size_t)vc;
            t0 = out_color[ob]; t1 = out_color[ob + 1]; t2 = out_color[ob + 2];
        } else {
            t0 = texT[(size_t)(3 * vc)     * 64 + b];
            t1 = texT[(size_t)(3 * vc + 1) * 64 + b];
            t2 = texT[(size_t)(3 * vc + 2) * 64 + b];
        }
        float tex3[3] = {t0, t1, t2};
#pragma unroll
        for (int c = 0; c < 3; c++) {
            float rgb = Y0 * g[0 + c] + Y1 * g[3 + c] + Y2 * g[6 + c] + Y3 * g[9 + c] +
                        Y4 * g[12 + c] + Y5 * g[15 + c] + Y6 * g[18 + c] + Y7 * g[21 + c] +
                        Y8 * g[24 + c];
            col[vr][c] = rgb * tex3[c];
        }
    }

#pragma unroll
    for (int vr = 0; vr < 8; vr++)
#pragma unroll
        for (int c = 0; c < 3; c++)
            sh[b * 97 + (wave * 8 + vr) * 3 + c] = vert[vr][c];
    __syncthreads();
#pragma unroll 4
    for (int it = 0; it < 24; it++) {
        int f = it * 256 + threadIdx.x;
        int bb = f / 96, k = f - bb * 96;
        if (k < kmax)
            __builtin_nontemporal_store(sh[bb * 97 + k],
                                        out_vertex + (size_t)bb * NR + 3 * (size_t)v0 + k);
    }
    __syncthreads();

#pragma unroll
    for (int vr = 0; vr < 8; vr++)
#pragma unroll
        for (int c = 0; c < 3; c++)
            sh[b * 97 + (wave * 8 + vr) * 3 + c] = col[vr][c];
    __syncthreads();
#pragma unroll 4
    for (int it = 0; it < 24; it++) {
        int f = it * 256 + threadIdx.x;
        int bb = f / 96, k = f - bb * 96;
        if (k < kmax)
            __builtin_nontemporal_store(sh[bb * 97 + k],
                                        out_color + (size_t)bb * NR + 3 * (size_t)v0 + k);
    }
}

__global__ __launch_bounds__(64) void k_landmark(
    const float* __restrict__ shapeT, const int* __restrict__ keypoints,
    const float* __restrict__ rotM, const float* __restrict__ coeffs,
    const float* __restrict__ P,
    float* __restrict__ out_lm)
{
    int l = blockIdx.x;
    int b = threadIdx.x;
    int kp = keypoints[l];

    float m0 = rotM[b * 9 + 0], m1 = rotM[b * 9 + 1], m2 = rotM[b * 9 + 2];
    float m3 = rotM[b * 9 + 3], m4 = rotM[b * 9 + 4], m5 = rotM[b * 9 + 5];
    float m6 = rotM[b * 9 + 6], m7 = rotM[b * 9 + 7], m8 = rotM[b * 9 + 8];
    float tx = coeffs[b * 257 + 254], ty = coeffs[b * 257 + 255], tz = coeffs[b * 257 + 256];

    float sx0 = shapeT[(size_t)(3 * kp)     * 64 + b];
    float sy0 = shapeT[(size_t)(3 * kp + 1) * 64 + b];
    float sz0 = shapeT[(size_t)(3 * kp + 2) * 64 + b];

    float x = m0 * sx0 + m1 * sy0 + m2 * sz0 + tx;
    float y = m3 * sx0 + m4 * sy0 + m5 * sz0 + ty;
    float z = 10.0f - (m6 * sx0 + m7 * sy0 + m8 * sz0 + tz);

    float p0 = x * P[0] + y * P[3] + z * P[6];
    float p1 = x * P[1] + y * P[4] + z * P[7];
    float p2 = x * P[2] + y * P[5] + z * P[8];

    size_t o = ((size_t)b * 68 + l) * 2;
    out_lm[o]     = p0 / p2;
    out_lm[o + 1] = p1 / p2;
}

extern "C" void kernel_launch(void* const* d_in, const int* in_sizes, int n_in,
                              void* d_out, int out_size, void* d_ws, size_t ws_size,
                              hipStream_t stream) {
    const float* coeffs    = (const float*)d_in[0];
    const float* meanshape = (const float*)d_in[1];
    const float* idBase    = (const float*)d_in[2];
    const float* exBase    = (const float*)d_in[3];
    const float* meantex   = (const float*)d_in[4];
    const float* texBase   = (const float*)d_in[5];
    const float* persc     = (const float*)d_in[6];
    const float* init_lit  = (const float*)d_in[7];
    const int*   point_buf = (const int*)d_in[8];
    const int*   face_buf  = (const int*)d_in[9];
    const int*   keypoints = (const int*)d_in[10];

    float* ws = (float*)d_ws;
    float* rotM = ws + WS_ROT;
    float* gm   = ws + WS_GM;
    float* ctrS = ws + WS_CTRS;
    float* ctrT = ws + WS_CTRT;

    float* out_vertex = (float*)d_out;
    float* out_color  = out_vertex + (size_t)NB * NR;
    float* out_lm     = out_color  + (size_t)NB * NR;

    size_t sh3_len = (size_t)N_V * 64 * 3;          // == NR*64
    size_t fn3_len = (size_t)(N_F + 1) * 64 * 3;

    size_t need_new = ((size_t)WS_MAIN + 2 * sh3_len + fn3_len) * sizeof(float);
    size_t need_tex = ((size_t)WS_MAIN + 2 * sh3_len) * sizeof(float);

    k_setup_rot<<<1, 64, 0, stream>>>(coeffs, init_lit, rotM, gm);
    k_transpose<<<224, 64, 0, stream>>>(coeffs, ctrS, ctrT);

    const int GB = (NR + 63) / 64;

    if (ws_size >= need_new) {
        float* shape3 = ws + WS_MAIN;
        float* tex3   = shape3 + sh3_len;
        float* fnT3   = tex3 + sh3_len;

        k_gemm_shape3<<<GB, 256, 0, stream>>>(idBase, exBase, meanshape, ctrS, shape3);

        const int FB = (N_F + 1 + 31) / 32;   // 2213 >= GB=1674
        k_fn_texgemm<<<GB + FB, 256, 0, stream>>>(texBase, meantex, ctrT,
                                                  shape3, face_buf, tex3, fnT3, GB);

        const int VB = (N_V + 15) / 16;
        const int LB = (68 + 3) / 4;
        k_vertex_lm<<<VB + LB, 256, 0, stream>>>(shape3, tex3, fnT3, rotM, gm,
                                                 coeffs, point_buf, keypoints, persc,
                                                 out_vertex, out_color, out_lm, VB);
    } else {
        int tex_transposed = (ws_size >= need_tex) ? 1 : 0;
        float* shapeT = ws + WS_MAIN;
        float* texT   = tex_transposed ? (shapeT + sh3_len) : out_color;

        k_gemm_tile<<<GB, 256, 0, stream>>>(idBase, exBase, texBase, meanshape,
                                            meantex, ctrS, ctrT, shapeT, texT,
                                            tex_transposed);
        int vb = (N_V + 31) / 32;
        k_vertex<<<vb, 256, 0, stream>>>(shapeT, tex_transposed ? texT : nullptr,
                                         rotM, gm, coeffs, point_buf, face_buf,
                                         out_vertex, out_color,
                                         tex_transposed ? 0 : 1);
        k_landmark<<<68, 64, 0, stream>>>(shapeT, keypoints, rotM, coeffs, persc, out_lm);
    }
}

// Round 9
// 287.622 us; speedup vs baseline: 1.0417x; 1.0417x over previous
//
#include <hip/hip_runtime.h>

#define N_V 35709
#define N_F 70789
#define NR  (3*N_V)   // 107127
#define NB  64

// ws layout (floats):
//   rotM  : NB*9   = 576    @ 0
//   gm    : NB*27  = 1728   @ 576
//   ctrS  : 144*NB = 9216   @ 2304   (id+ex coeffs, [j][b])
//   ctrT  : 80*NB  = 5120   @ 11520  (tex coeffs, [j][b])
//   shapeT: NR*64          @ 16640   (pre-rotation face_shape, TRANSPOSED [i][b])
//   texT  : NR*64          @ +NR*64
//   fnT3  : (N_F+1)*64*3   @ +NR*64    (unit face normals, float3 per (f,b), sentinel 0 at f=N_F)
//   shape3: N_V*64*3       @ +fnT3     (shape packed float3 per (v,b), written by gemm)
#define WS_ROT    0
#define WS_GM     576
#define WS_CTRS   2304
#define WS_CTRT   11520
#define WS_SHAPET 16640

__global__ __launch_bounds__(64) void k_setup_rot(
    const float* __restrict__ coeffs, const float* __restrict__ init_lit,
    float* __restrict__ rotM, float* __restrict__ gm)
{
    int b = threadIdx.x;
    const float* cb = coeffs + b * 257;

    float ax = cb[224], ay = cb[225], az = cb[226];
    float cx = cosf(ax), sx = sinf(ax);
    float cy = cosf(ay), sy = sinf(ay);
    float cz = cosf(az), sz = sinf(az);
    float m[9];
    m[0] = cz * cy;
    m[1] = cz * sy * sx - sz * cx;
    m[2] = sz * sx + cz * sy * cx;
    m[3] = sz * cy;
    m[4] = cz * cx + sz * sy * sx;
    m[5] = sz * sy * cx - cz * sx;
    m[6] = -sy;
    m[7] = cy * sx;
    m[8] = cy * cx;
#pragma unroll
    for (int k = 0; k < 9; k++) rotM[b * 9 + k] = m[k];

#pragma unroll
    for (int k = 0; k < 9; k++) {
        float il = init_lit[k];
#pragma unroll
        for (int c = 0; c < 3; c++)
            gm[b * 27 + k * 3 + c] = cb[227 + c * 9 + k] + il;
    }
}

// grid = 224 blocks of 64: block j transposes coeff column j into [j][b]
__global__ __launch_bounds__(64) void k_transpose(
    const float* __restrict__ coeffs,
    float* __restrict__ ctrS, float* __restrict__ ctrT)
{
    int j = blockIdx.x;
    int b = threadIdx.x;
    float v = coeffs[b * 257 + j];
    if (j < 144) ctrS[j * 64 + b] = v;
    else         ctrT[(j - 144) * 64 + b] = v;
}

// LDS-tiled register-blocked GEMM (round-7 structure) + double-buffered staging
// (1 barrier/chunk instead of 2; next chunk's global loads issued before compute)
// + dual-write shape epilogue (shapeT float4 + optional shape3 scatter, killing
// the separate repack kernel). FMA order identical to round 7.
__global__ __launch_bounds__(256) void k_gemm_tile(
    const float* __restrict__ idBase, const float* __restrict__ exBase,
    const float* __restrict__ texBase, const float* __restrict__ meanshape,
    const float* __restrict__ meantex,
    const float* __restrict__ ctrS, const float* __restrict__ ctrT,
    float* __restrict__ shapeT,      // ws, [i][64]
    float* __restrict__ texT,        // [i][64] if transposed, else out_color [b][NR]
    float* __restrict__ shape3,      // [(v*64+b)*3+c], written iff write_s3
    int write_s3, int tex_transposed)
{
    __shared__ __align__(16) float As[2][16][68];
    __shared__ __align__(16) float Bs[2][16][64];

    const int t  = threadIdx.x;
    const int tn = t & 15;       // batch group
    const int tm = t >> 4;       // row group (0..15)
    const int r0 = blockIdx.x * 64;

    const int srow = t >> 2;     // staging: row 0..63
    const int sc   = t & 3;      // staging: col group 0..3
    int srg = r0 + srow; if (srg > NR - 1) srg = NR - 1;

    float acc[4][4];

    // ================= shape: 9 K-chunks (5 id + 4 ex), double-buffered =========
#pragma unroll
    for (int i = 0; i < 4; i++)
#pragma unroll
        for (int j = 0; j < 4; j++) acc[i][j] = 0.f;

    // prologue: stage chunk 0 into buffer 0
    {
        float4 v = *(const float4*)(idBase + (size_t)srg * 80 + sc * 4);
        As[0][sc * 4 + 0][srow] = v.x;
        As[0][sc * 4 + 1][srow] = v.y;
        As[0][sc * 4 + 2][srow] = v.z;
        As[0][sc * 4 + 3][srow] = v.w;
        ((float4*)&Bs[0][0][0])[t] = ((const float4*)ctrS)[t];
    }
    __syncthreads();

    for (int kc = 0; kc < 9; kc++) {
        const int cur = kc & 1;
        const int nxt = cur ^ 1;
        float4 pa, pb;
        const bool havenext = (kc + 1 < 9);
        if (havenext) {
            const float* src;
            int ld, k0;
            if (kc + 1 < 5) { src = idBase; ld = 80; k0 = (kc + 1) * 16; }
            else            { src = exBase; ld = 64; k0 = (kc + 1 - 5) * 16; }
            pa = *(const float4*)(src + (size_t)srg * ld + k0 + sc * 4);
            pb = ((const float4*)(ctrS + (size_t)(kc + 1) * 16 * 64))[t];
        }

#pragma unroll
        for (int k = 0; k < 16; k++) {
            float4 a = *(const float4*)&As[cur][k][tm * 4];
            float4 b = *(const float4*)&Bs[cur][k][tn * 4];
            float av[4] = {a.x, a.y, a.z, a.w};
            float bv[4] = {b.x, b.y, b.z, b.w};
#pragma unroll
            for (int i = 0; i < 4; i++)
#pragma unroll
                for (int j = 0; j < 4; j++)
                    acc[i][j] += av[i] * bv[j];
        }

        if (havenext) {
            As[nxt][sc * 4 + 0][srow] = pa.x;
            As[nxt][sc * 4 + 1][srow] = pa.y;
            As[nxt][sc * 4 + 2][srow] = pa.z;
            As[nxt][sc * 4 + 3][srow] = pa.w;
            ((float4*)&Bs[nxt][0][0])[t] = pb;
        }
        __syncthreads();
    }

    // epilogue shape: += meanshape; shapeT float4 coalesced (+ shape3 scatter)
#pragma unroll
    for (int i = 0; i < 4; i++) {
        int rg = r0 + tm * 4 + i;
        if (rg < NR) {
            float ms = meanshape[rg];
            float s0 = acc[i][0] + ms, s1 = acc[i][1] + ms;
            float s2 = acc[i][2] + ms, s3 = acc[i][3] + ms;
            float4 o = {s0, s1, s2, s3};
            *(float4*)(shapeT + (size_t)rg * 64 + tn * 4) = o;
            if (write_s3) {
                int v = rg / 3;
                int c = rg - v * 3;
                float* p = shape3 + ((size_t)v * 64 + tn * 4) * 3 + c;
                p[0] = s0; p[3] = s1; p[6] = s2; p[9] = s3;
            }
        }
    }

    // ================= tex: 5 K-chunks, double-buffered =========
#pragma unroll
    for (int i = 0; i < 4; i++)
#pragma unroll
        for (int j = 0; j < 4; j++) acc[i][j] = 0.f;

    // prologue: stage tex chunk 0 into buffer 0 (all reads of As[0]/Bs[0] from the
    // final shape iteration completed before its trailing barrier)
    {
        float4 v = *(const float4*)(texBase + (size_t)srg * 80 + sc * 4);
        As[0][sc * 4 + 0][srow] = v.x;
        As[0][sc * 4 + 1][srow] = v.y;
        As[0][sc * 4 + 2][srow] = v.z;
        As[0][sc * 4 + 3][srow] = v.w;
        ((float4*)&Bs[0][0][0])[t] = ((const float4*)ctrT)[t];
    }
    __syncthreads();

    for (int kc = 0; kc < 5; kc++) {
        const int cur = kc & 1;
        const int nxt = cur ^ 1;
        float4 pa, pb;
        const bool havenext = (kc + 1 < 5);
        if (havenext) {
            int k0 = (kc + 1) * 16;
            pa = *(const float4*)(texBase + (size_t)srg * 80 + k0 + sc * 4);
            pb = ((const float4*)(ctrT + (size_t)(kc + 1) * 16 * 64))[t];
        }

#pragma unroll
        for (int k = 0; k < 16; k++) {
            float4 a = *(const float4*)&As[cur][k][tm * 4];
            float4 b = *(const float4*)&Bs[cur][k][tn * 4];
            float av[4] = {a.x, a.y, a.z, a.w};
            float bv[4] = {b.x, b.y, b.z, b.w};
#pragma unroll
            for (int i = 0; i < 4; i++)
#pragma unroll
                for (int j = 0; j < 4; j++)
                    acc[i][j] += av[i] * bv[j];
        }

        if (havenext) {
            As[nxt][sc * 4 + 0][srow] = pa.x;
            As[nxt][sc * 4 + 1][srow] = pa.y;
            As[nxt][sc * 4 + 2][srow] = pa.z;
            As[nxt][sc * 4 + 3][srow] = pa.w;
            ((float4*)&Bs[nxt][0][0])[t] = pb;
        }
        __syncthreads();
    }

    const float inv255 = 1.0f / 255.0f;
    if (tex_transposed) {
#pragma unroll
        for (int i = 0; i < 4; i++) {
            int rg = r0 + tm * 4 + i;
            if (rg < NR) {
                float mt = meantex[rg];
                float4 o = {(acc[i][0] + mt) * inv255, (acc[i][1] + mt) * inv255,
                            (acc[i][2] + mt) * inv255, (acc[i][3] + mt) * inv255};
                *(float4*)(texT + (size_t)rg * 64 + tn * 4) = o;
            }
        }
    } else {
        // tiny-ws fallback: out_color [b][NR] layout (uncoalesced but correct)
#pragma unroll
        for (int i = 0; i < 4; i++) {
            int rg = r0 + tm * 4 + i;
            if (rg < NR) {
                float mt = meantex[rg];
#pragma unroll
                for (int j = 0; j < 4; j++)
                    texT[(size_t)(tn * 4 + j) * NR + rg] = (acc[i][j] + mt) * inv255;
            }
        }
    }
}

// Face normals from shape3: 3 packed float3 gathers per face.
// Covers f = 0..N_F inclusive; f==N_F is the sentinel zero row.
__global__ __launch_bounds__(256) void k_facenorm3(
    const float* __restrict__ shape3,
    const int* __restrict__ face_buf,
    float* __restrict__ fnT3)           // [(f*64+b)*3 + c]
{
    int wave = threadIdx.x >> 6;
    int b    = threadIdx.x & 63;
    int f0   = blockIdx.x * 32 + wave * 8;
#pragma unroll
    for (int fr = 0; fr < 8; fr++) {
        int f = f0 + fr;
        if (f < N_F) {
            int i0 = face_buf[f * 3 + 0];
            int i1 = face_buf[f * 3 + 1];
            int i2 = face_buf[f * 3 + 2];
            const float* p0 = shape3 + ((size_t)i0 * 64 + b) * 3;
            const float* p1 = shape3 + ((size_t)i1 * 64 + b) * 3;
            const float* p2 = shape3 + ((size_t)i2 * 64 + b) * 3;
            float p0x = p0[0], p0y = p0[1], p0z = p0[2];
            float p1x = p1[0], p1y = p1[1], p1z = p1[2];
            float p2x = p2[0], p2y = p2[1], p2z = p2[2];
            float e1x = p0x - p1x, e1y = p0y - p1y, e1z = p0z - p1z;
            float e2x = p1x - p2x, e2y = p1y - p2y, e2z = p1z - p2z;
            float ccx = e1y * e2z - e1z * e2y;
            float ccy = e1z * e2x - e1x * e2z;
            float ccz = e1x * e2y - e1y * e2x;
            float l = sqrtf(ccx * ccx + ccy * ccy + ccz * ccz);
            float inv = 1.0f / fmaxf(l, 1e-12f);
            float* o = fnT3 + ((size_t)f * 64 + b) * 3;
            o[0] = ccx * inv; o[1] = ccy * inv; o[2] = ccz * inv;
        } else if (f == N_F) {
            float* o = fnT3 + ((size_t)f * 64 + b) * 3;
            o[0] = 0.f; o[1] = 0.f; o[2] = 0.f;
        }
    }
}

// Fallback facenorm reading shapeT directly (no shape3 ws room). Writes fnT3 layout.
__global__ __launch_bounds__(256) void k_facenorm(
    const float* __restrict__ shapeT,   // [i][64]
    const int* __restrict__ face_buf,
    float* __restrict__ fnT3)
{
    int wave = threadIdx.x >> 6;
    int b    = threadIdx.x & 63;
    int f0   = blockIdx.x * 32 + wave * 8;
#pragma unroll
    for (int fr = 0; fr < 8; fr++) {
        int f = f0 + fr;
        if (f < N_F) {
            int i0 = face_buf[f * 3 + 0];
            int i1 = face_buf[f * 3 + 1];
            int i2 = face_buf[f * 3 + 2];
            float p0x = shapeT[(size_t)(3 * i0)     * 64 + b];
            float p0y = shapeT[(size_t)(3 * i0 + 1) * 64 + b];
            float p0z = shapeT[(size_t)(3 * i0 + 2) * 64 + b];
            float p1x = shapeT[(size_t)(3 * i1)     * 64 + b];
            float p1y = shapeT[(size_t)(3 * i1 + 1) * 64 + b];
            float p1z = shapeT[(size_t)(3 * i1 + 2) * 64 + b];
            float p2x = shapeT[(size_t)(3 * i2)     * 64 + b];
            float p2y = shapeT[(size_t)(3 * i2 + 1) * 64 + b];
            float p2z = shapeT[(size_t)(3 * i2 + 2) * 64 + b];
            float e1x = p0x - p1x, e1y = p0y - p1y, e1z = p0z - p1z;
            float e2x = p1x - p2x, e2y = p1y - p2y, e2z = p1z - p2z;
            float ccx = e1y * e2z - e1z * e2y;
            float ccy = e1z * e2x - e1x * e2z;
            float ccz = e1x * e2y - e1y * e2x;
            float l = sqrtf(ccx * ccx + ccy * ccy + ccz * ccz);
            float inv = 1.0f / fmaxf(l, 1e-12f);
            float* o = fnT3 + ((size_t)f * 64 + b) * 3;
            o[0] = ccx * inv; o[1] = ccy * inv; o[2] = ccz * inv;
        } else if (f == N_F) {
            float* o = fnT3 + ((size_t)f * 64 + b) * 3;
            o[0] = 0.f; o[1] = 0.f; o[2] = 0.f;
        }
    }
}

// Vertex kernel: 8 unconditional float3 fnT3 gathers per vertex (sentinel handles f==N_F).
// All point_buf / own-row loads hoisted ahead of gather consumption for MLP.
__global__ __launch_bounds__(256) void k_vertex_fn(
    const float* __restrict__ shapeT,  // [i][64]
    const float* __restrict__ texT,    // [i][64]
    const float* __restrict__ fnT3,    // [(f*64+b)*3 + c]
    const float* __restrict__ rotM, const float* __restrict__ gm,
    const float* __restrict__ coeffs,
    const int* __restrict__ point_buf,
    float* __restrict__ out_vertex, float* __restrict__ out_color)
{
    __shared__ float sh[64 * 49];   // [b][48] padded to 49
    int wave = threadIdx.x >> 6;
    int b    = threadIdx.x & 63;
    int v0   = blockIdx.x * 16;
    int nvalid = N_V - v0; if (nvalid > 16) nvalid = 16;
    int kmax = 3 * nvalid;

    float m0 = rotM[b * 9 + 0], m1 = rotM[b * 9 + 1], m2 = rotM[b * 9 + 2];
    float m3 = rotM[b * 9 + 3], m4 = rotM[b * 9 + 4], m5 = rotM[b * 9 + 5];
    float m6 = rotM[b * 9 + 6], m7 = rotM[b * 9 + 7], m8 = rotM[b * 9 + 8];
    float tx = coeffs[b * 257 + 254], ty = coeffs[b * 257 + 255], tz = coeffs[b * 257 + 256];
    float g[27];
#pragma unroll
    for (int k = 0; k < 27; k++) g[k] = gm[b * 27 + k];

    const float A0C0 = 0.8862269254527580f;
    const float A1C1 = 1.7724538509055159f;
    const float A2C2 = 2.4270323912f;
    const float C6   = 0.7006239022f;
    const float C8   = 1.2135161956f;

    // ---- hoisted loads: point_buf indices + own shape/tex rows for all 4 vertices ----
    int pf[4][8];
    float sxv[4], syv[4], szv[4];
    float t0v[4], t1v[4], t2v[4];
#pragma unroll
    for (int vr = 0; vr < 4; vr++) {
        int v = v0 + wave * 4 + vr;
        int vc = (v < N_V) ? v : (N_V - 1);
#pragma unroll
        for (int k = 0; k < 8; k++) pf[vr][k] = point_buf[vc * 8 + k];
        sxv[vr] = shapeT[(size_t)(3 * vc)     * 64 + b];
        syv[vr] = shapeT[(size_t)(3 * vc + 1) * 64 + b];
        szv[vr] = shapeT[(size_t)(3 * vc + 2) * 64 + b];
        t0v[vr] = texT[(size_t)(3 * vc)     * 64 + b];
        t1v[vr] = texT[(size_t)(3 * vc + 1) * 64 + b];
        t2v[vr] = texT[(size_t)(3 * vc + 2) * 64 + b];
    }

    float vert[4][3];
    float col[4][3];

#pragma unroll
    for (int vr = 0; vr < 4; vr++) {
        // gather 8 float3 normals (unconditional; f==N_F is zero sentinel)
        float fx[8], fy[8], fz[8];
#pragma unroll
        for (int k = 0; k < 8; k++) {
            const float* fp = fnT3 + ((size_t)pf[vr][k] * 64 + b) * 3;
            fx[k] = fp[0]; fy[k] = fp[1]; fz[k] = fp[2];
        }

        float vx = m0 * sxv[vr] + m1 * syv[vr] + m2 * szv[vr] + tx;
        float vy = m3 * sxv[vr] + m4 * syv[vr] + m5 * szv[vr] + ty;
        float vz = m6 * sxv[vr] + m7 * syv[vr] + m8 * szv[vr] + tz;
        vert[vr][0] = vx; vert[vr][1] = vy; vert[vr][2] = 10.0f - vz;

        float nx = 0.f, ny = 0.f, nz = 0.f;
#pragma unroll
        for (int k = 0; k < 8; k++) { nx += fx[k]; ny += fy[k]; nz += fz[k]; }
        float l = sqrtf(nx * nx + ny * ny + nz * nz);
        float inv = 1.0f / fmaxf(l, 1e-12f);
        nx *= inv; ny *= inv; nz *= inv;

        float rx = m0 * nx + m1 * ny + m2 * nz;
        float ry = m3 * nx + m4 * ny + m5 * nz;
        float rz = m6 * nx + m7 * ny + m8 * nz;

        float Y0 = A0C0;
        float Y1 = -A1C1 * ry;
        float Y2 =  A1C1 * rz;
        float Y3 = -A1C1 * rx;
        float Y4 =  A2C2 * rx * ry;
        float Y5 = -A2C2 * ry * rz;
        float Y6 =  C6 * (3.f * rz * rz - 1.f);
        float Y7 = -A2C2 * rx * rz;
        float Y8 =  C8 * (rx * rx - ry * ry);

        float tex3[3] = {t0v[vr], t1v[vr], t2v[vr]};
#pragma unroll
        for (int c = 0; c < 3; c++) {
            float rgb = Y0 * g[0 + c] + Y1 * g[3 + c] + Y2 * g[6 + c] + Y3 * g[9 + c] +
                        Y4 * g[12 + c] + Y5 * g[15 + c] + Y6 * g[18 + c] + Y7 * g[21 + c] +
                        Y8 * g[24 + c];
            col[vr][c] = rgb * tex3[c];
        }
    }

    // ---- stage + flush vertex ----
#pragma unroll
    for (int vr = 0; vr < 4; vr++)
#pragma unroll
        for (int c = 0; c < 3; c++)
            sh[b * 49 + (wave * 4 + vr) * 3 + c] = vert[vr][c];
    __syncthreads();
#pragma unroll 4
    for (int it = 0; it < 12; it++) {
        int f = it * 256 + threadIdx.x;
        int bb = f / 48, k = f - bb * 48;
        if (k < kmax)
            __builtin_nontemporal_store(sh[bb * 49 + k],
                                        out_vertex + (size_t)bb * NR + 3 * (size_t)v0 + k);
    }
    __syncthreads();

    // ---- stage + flush color ----
#pragma unroll
    for (int vr = 0; vr < 4; vr++)
#pragma unroll
        for (int c = 0; c < 3; c++)
            sh[b * 49 + (wave * 4 + vr) * 3 + c] = col[vr][c];
    __syncthreads();
#pragma unroll 4
    for (int it = 0; it < 12; it++) {
        int f = it * 256 + threadIdx.x;
        int bb = f / 48, k = f - bb * 48;
        if (k < kmax)
            __builtin_nontemporal_store(sh[bb * 49 + k],
                                        out_color + (size_t)bb * NR + 3 * (size_t)v0 + k);
    }
}

// FALLBACK (ws too small for fnT3): original fused kernel, unchanged.
__global__ __launch_bounds__(256) void k_vertex(
    const float* __restrict__ shapeT,
    const float* __restrict__ texT,
    const float* __restrict__ rotM, const float* __restrict__ gm,
    const float* __restrict__ coeffs,
    const int* __restrict__ point_buf, const int* __restrict__ face_buf,
    float* __restrict__ out_vertex, float* __restrict__ out_color,
    int tex_in_out)
{
    __shared__ float sh[64 * 97];
    int wave = threadIdx.x >> 6;
    int b    = threadIdx.x & 63;
    int v0   = blockIdx.x * 32;
    int nvalid = N_V - v0; if (nvalid > 32) nvalid = 32;
    int kmax = 3 * nvalid;

    float m0 = rotM[b * 9 + 0], m1 = rotM[b * 9 + 1], m2 = rotM[b * 9 + 2];
    float m3 = rotM[b * 9 + 3], m4 = rotM[b * 9 + 4], m5 = rotM[b * 9 + 5];
    float m6 = rotM[b * 9 + 6], m7 = rotM[b * 9 + 7], m8 = rotM[b * 9 + 8];
    float tx = coeffs[b * 257 + 254], ty = coeffs[b * 257 + 255], tz = coeffs[b * 257 + 256];
    float g[27];
#pragma unroll
    for (int k = 0; k < 27; k++) g[k] = gm[b * 27 + k];

    const float A0C0 = 0.8862269254527580f;
    const float A1C1 = 1.7724538509055159f;
    const float A2C2 = 2.4270323912f;
    const float C6   = 0.7006239022f;
    const float C8   = 1.2135161956f;

    float vert[8][3];
    float col[8][3];

#pragma unroll
    for (int vr = 0; vr < 8; vr++) {
        int v = v0 + wave * 8 + vr;
        bool valid = (v < N_V);
        int vc = valid ? v : (N_V - 1);

        float sx0 = shapeT[(size_t)(3 * vc)     * 64 + b];
        float sy0 = shapeT[(size_t)(3 * vc + 1) * 64 + b];
        float sz0 = shapeT[(size_t)(3 * vc + 2) * 64 + b];

        float vx = m0 * sx0 + m1 * sy0 + m2 * sz0 + tx;
        float vy = m3 * sx0 + m4 * sy0 + m5 * sz0 + ty;
        float vz = m6 * sx0 + m7 * sy0 + m8 * sz0 + tz;
        vert[vr][0] = vx; vert[vr][1] = vy; vert[vr][2] = 10.0f - vz;

        float nx = 0.f, ny = 0.f, nz = 0.f;
#pragma unroll
        for (int k = 0; k < 8; k++) {
            int f = point_buf[vc * 8 + k];
            if (f < N_F) {
                int i0 = face_buf[f * 3], i1 = face_buf[f * 3 + 1], i2 = face_buf[f * 3 + 2];
                float p0x = shapeT[(size_t)(3 * i0)     * 64 + b];
                float p0y = shapeT[(size_t)(3 * i0 + 1) * 64 + b];
                float p0z = shapeT[(size_t)(3 * i0 + 2) * 64 + b];
                float p1x = shapeT[(size_t)(3 * i1)     * 64 + b];
                float p1y = shapeT[(size_t)(3 * i1 + 1) * 64 + b];
                float p1z = shapeT[(size_t)(3 * i1 + 2) * 64 + b];
                float p2x = shapeT[(size_t)(3 * i2)     * 64 + b];
                float p2y = shapeT[(size_t)(3 * i2 + 1) * 64 + b];
                float p2z = shapeT[(size_t)(3 * i2 + 2) * 64 + b];
                float e1x = p0x - p1x, e1y = p0y - p1y, e1z = p0z - p1z;
                float e2x = p1x - p2x, e2y = p1y - p2y, e2z = p1z - p2z;
                float ccx = e1y * e2z - e1z * e2y;
                float ccy = e1z * e2x - e1x * e2z;
                float ccz = e1x * e2y - e1y * e2x;
                float l = sqrtf(ccx * ccx + ccy * ccy + ccz * ccz);
                float inv = 1.0f / fmaxf(l, 1e-12f);
                nx += ccx * inv; ny += ccy * inv; nz += ccz * inv;
            }
        }
        float l = sqrtf(nx * nx + ny * ny + nz * nz);
        float inv = 1.0f / fmaxf(l, 1e-12f);
        nx *= inv; ny *= inv; nz *= inv;

        float rx = m0 * nx + m1 * ny + m2 * nz;
        float ry = m3 * nx + m4 * ny + m5 * nz;
        float rz = m6 * nx + m7 * ny + m8 * nz;

        float Y0 = A0C0;
        float Y1 = -A1C1 * ry;
        float Y2 =  A1C1 * rz;
        float Y3 = -A1C1 * rx;
        float Y4 =  A2C2 * rx * ry;
        float Y5 = -A2C2 * ry * rz;
        float Y6 =  C6 * (3.f * rz * rz - 1.f);
        float Y7 = -A2C2 * rx * rz;
        float Y8 =  C8 * (rx * rx - ry * ry);

        float t0, t1, t2;
        if (tex_in_out) {
            size_t ob = (size_t)b * NR + 3 * (size_t)vc;
            t0 = out_color[ob]; t1 = out_color[ob + 1]; t2 = out_color[ob + 2];
        } else {
            t0 = texT[(size_t)(3 * vc)     * 64 + b];
            t1 = texT[(size_t)(3 * vc + 1) * 64 + b];
            t2 = texT[(size_t)(3 * vc + 2) * 64 + b];
        }
        float tex3[3] = {t0, t1, t2};
#pragma unroll
        for (int c = 0; c < 3; c++) {
            float rgb = Y0 * g[0 + c] + Y1 * g[3 + c] + Y2 * g[6 + c] + Y3 * g[9 + c] +
                        Y4 * g[12 + c] + Y5 * g[15 + c] + Y6 * g[18 + c] + Y7 * g[21 + c] +
                        Y8 * g[24 + c];
            col[vr][c] = rgb * tex3[c];
        }
    }

#pragma unroll
    for (int vr = 0; vr < 8; vr++)
#pragma unroll
        for (int c = 0; c < 3; c++)
            sh[b * 97 + (wave * 8 + vr) * 3 + c] = vert[vr][c];
    __syncthreads();
#pragma unroll 4
    for (int it = 0; it < 24; it++) {
        int f = it * 256 + threadIdx.x;
        int bb = f / 96, k = f - bb * 96;
        if (k < kmax)
            __builtin_nontemporal_store(sh[bb * 97 + k],
                                        out_vertex + (size_t)bb * NR + 3 * (size_t)v0 + k);
    }
    __syncthreads();

#pragma unroll
    for (int vr = 0; vr < 8; vr++)
#pragma unroll
        for (int c = 0; c < 3; c++)
            sh[b * 97 + (wave * 8 + vr) * 3 + c] = col[vr][c];
    __syncthreads();
#pragma unroll 4
    for (int it = 0; it < 24; it++) {
        int f = it * 256 + threadIdx.x;
        int bb = f / 96, k = f - bb * 96;
        if (k < kmax)
            __builtin_nontemporal_store(sh[bb * 97 + k],
                                        out_color + (size_t)bb * NR + 3 * (size_t)v0 + k);
    }
}

// grid = 68 blocks of 64 (lane = batch); recompute transform from shapeT
__global__ __launch_bounds__(64) void k_landmark(
    const float* __restrict__ shapeT, const int* __restrict__ keypoints,
    const float* __restrict__ rotM, const float* __restrict__ coeffs,
    const float* __restrict__ P,
    float* __restrict__ out_lm)
{
    int l = blockIdx.x;
    int b = threadIdx.x;
    int kp = keypoints[l];

    float m0 = rotM[b * 9 + 0], m1 = rotM[b * 9 + 1], m2 = rotM[b * 9 + 2];
    float m3 = rotM[b * 9 + 3], m4 = rotM[b * 9 + 4], m5 = rotM[b * 9 + 5];
    float m6 = rotM[b * 9 + 6], m7 = rotM[b * 9 + 7], m8 = rotM[b * 9 + 8];
    float tx = coeffs[b * 257 + 254], ty = coeffs[b * 257 + 255], tz = coeffs[b * 257 + 256];

    float sx0 = shapeT[(size_t)(3 * kp)     * 64 + b];
    float sy0 = shapeT[(size_t)(3 * kp + 1) * 64 + b];
    float sz0 = shapeT[(size_t)(3 * kp + 2) * 64 + b];

    float x = m0 * sx0 + m1 * sy0 + m2 * sz0 + tx;
    float y = m3 * sx0 + m4 * sy0 + m5 * sz0 + ty;
    float z = 10.0f - (m6 * sx0 + m7 * sy0 + m8 * sz0 + tz);

    float p0 = x * P[0] + y * P[3] + z * P[6];
    float p1 = x * P[1] + y * P[4] + z * P[7];
    float p2 = x * P[2] + y * P[5] + z * P[8];

    size_t o = ((size_t)b * 68 + l) * 2;
    out_lm[o]     = p0 / p2;
    out_lm[o + 1] = p1 / p2;
}

extern "C" void kernel_launch(void* const* d_in, const int* in_sizes, int n_in,
                              void* d_out, int out_size, void* d_ws, size_t ws_size,
                              hipStream_t stream) {
    const float* coeffs    = (const float*)d_in[0];
    const float* meanshape = (const float*)d_in[1];
    const float* idBase    = (const float*)d_in[2];
    const float* exBase    = (const float*)d_in[3];
    const float* meantex   = (const float*)d_in[4];
    const float* texBase   = (const float*)d_in[5];
    const float* persc     = (const float*)d_in[6];
    const float* init_lit  = (const float*)d_in[7];
    const int*   point_buf = (const int*)d_in[8];
    const int*   face_buf  = (const int*)d_in[9];
    const int*   keypoints = (const int*)d_in[10];

    float* ws = (float*)d_ws;
    float* rotM = ws + WS_ROT;
    float* gm   = ws + WS_GM;
    float* ctrS = ws + WS_CTRS;
    float* ctrT = ws + WS_CTRT;
    float* shapeT = ws + WS_SHAPET;

    float* out_vertex = (float*)d_out;
    float* out_color  = out_vertex + (size_t)NB * NR;
    float* out_lm     = out_color  + (size_t)NB * NR;

    size_t NRx64   = (size_t)NR * 64;
    size_t fn3_len = (size_t)(N_F + 1) * 64 * 3;
    size_t sh3_len = (size_t)N_V * 64 * 3;

    size_t need_tex = ((size_t)WS_SHAPET + 2 * NRx64) * sizeof(float);
    size_t need_fn  = need_tex + fn3_len * sizeof(float);
    size_t need_s3  = need_fn + sh3_len * sizeof(float);

    int tex_transposed = (ws_size >= need_tex) ? 1 : 0;
    int use_fn         = (ws_size >= need_fn) ? 1 : 0;
    int use_s3         = (ws_size >= need_s3) ? 1 : 0;

    float* texT   = tex_transposed ? (shapeT + NRx64) : out_color;
    float* fnT3   = shapeT + 2 * NRx64;
    float* shape3 = fnT3 + fn3_len;

    k_setup_rot<<<1, 64, 0, stream>>>(coeffs, init_lit, rotM, gm);
    k_transpose<<<224, 64, 0, stream>>>(coeffs, ctrS, ctrT);

    int gb = (NR + 63) / 64;
    k_gemm_tile<<<gb, 256, 0, stream>>>(idBase, exBase, texBase, meanshape,
                                        meantex, ctrS, ctrT, shapeT, texT,
                                        shape3, use_s3, tex_transposed);

    if (use_fn) {
        int fb = (N_F + 1 + 31) / 32;
        if (use_s3) {
            k_facenorm3<<<fb, 256, 0, stream>>>(shape3, face_buf, fnT3);
        } else {
            k_facenorm<<<fb, 256, 0, stream>>>(shapeT, face_buf, fnT3);
        }
        int vb = (N_V + 15) / 16;
        k_vertex_fn<<<vb, 256, 0, stream>>>(shapeT, texT, fnT3, rotM, gm, coeffs,
                                            point_buf, out_vertex, out_color);
    } else {
        int vb = (N_V + 31) / 32;
        k_vertex<<<vb, 256, 0, stream>>>(shapeT, tex_transposed ? texT : nullptr,
                                         rotM, gm, coeffs, point_buf, face_buf,
                                         out_vertex, out_color,
                                         tex_transposed ? 0 : 1);
    }

    k_landmark<<<68, 64, 0, stream>>>(shapeT, keypoints, rotM, coeffs, persc, out_lm);
}

// Round 10
// 285.438 us; speedup vs baseline: 1.0497x; 1.0077x over previous
//
#include <hip/hip_runtime.h>

#define N_V 35709
#define N_F 70789
#define NR  (3*N_V)   // 107127
#define NB  64

// ws layout (floats):
//   rotM  : NB*9   = 576    @ 0
//   gm    : NB*27  = 1728   @ 576
//   ctrS  : 144*NB = 9216   @ 2304   (id+ex coeffs, [j][b])
//   ctrT  : 80*NB  = 5120   @ 11520  (tex coeffs, [j][b])
//   shapeT: NR*64          @ 16640   (pre-rotation face_shape, TRANSPOSED [i][b])
//   texT  : NR*64          @ +NR*64
//   fnT3  : (N_F+1)*64*3   @ +NR*64    (unit face normals, float3 per (f,b), sentinel 0 at f=N_F)
//   shape3: N_V*64*3       @ +fnT3     (shape packed float3 per (v,b), written by gemm)
#define WS_ROT    0
#define WS_GM     576
#define WS_CTRS   2304
#define WS_CTRT   11520
#define WS_SHAPET 16640

__global__ __launch_bounds__(64) void k_setup_rot(
    const float* __restrict__ coeffs, const float* __restrict__ init_lit,
    float* __restrict__ rotM, float* __restrict__ gm)
{
    int b = threadIdx.x;
    const float* cb = coeffs + b * 257;

    float ax = cb[224], ay = cb[225], az = cb[226];
    float cx = cosf(ax), sx = sinf(ax);
    float cy = cosf(ay), sy = sinf(ay);
    float cz = cosf(az), sz = sinf(az);
    float m[9];
    m[0] = cz * cy;
    m[1] = cz * sy * sx - sz * cx;
    m[2] = sz * sx + cz * sy * cx;
    m[3] = sz * cy;
    m[4] = cz * cx + sz * sy * sx;
    m[5] = sz * sy * cx - cz * sx;
    m[6] = -sy;
    m[7] = cy * sx;
    m[8] = cy * cx;
#pragma unroll
    for (int k = 0; k < 9; k++) rotM[b * 9 + k] = m[k];

#pragma unroll
    for (int k = 0; k < 9; k++) {
        float il = init_lit[k];
#pragma unroll
        for (int c = 0; c < 3; c++)
            gm[b * 27 + k * 3 + c] = cb[227 + c * 9 + k] + il;
    }
}

// grid = 224 blocks of 64: block j transposes coeff column j into [j][b]
__global__ __launch_bounds__(64) void k_transpose(
    const float* __restrict__ coeffs,
    float* __restrict__ ctrS, float* __restrict__ ctrT)
{
    int j = blockIdx.x;
    int b = threadIdx.x;
    float v = coeffs[b * 257 + j];
    if (j < 144) ctrS[j * 64 + b] = v;
    else         ctrT[(j - 144) * 64 + b] = v;
}

// LDS-tiled register-blocked GEMM — round-7 verified single-buffered body
// (36 VGPR, 8.7 KB LDS, occupancy ~47%, measured 60 µs) + dual-write shape
// epilogue (shapeT float4 + optional shape3 scatter) which eliminates the
// separate repack kernel (round-9 verified numerically identical).
__global__ __launch_bounds__(256) void k_gemm_tile(
    const float* __restrict__ idBase, const float* __restrict__ exBase,
    const float* __restrict__ texBase, const float* __restrict__ meanshape,
    const float* __restrict__ meantex,
    const float* __restrict__ ctrS, const float* __restrict__ ctrT,
    float* __restrict__ shapeT,      // ws, [i][64]
    float* __restrict__ texT,        // [i][64] if transposed, else out_color [b][NR]
    float* __restrict__ shape3,      // [(v*64+b)*3+c], written iff write_s3
    int write_s3, int tex_transposed)
{
    __shared__ __align__(16) float As[16][68];
    __shared__ __align__(16) float Bs[16][64];

    const int t  = threadIdx.x;
    const int tn = t & 15;       // batch group
    const int tm = t >> 4;       // row group (0..15)
    const int r0 = blockIdx.x * 64;

    const int srow = t >> 2;     // staging: row 0..63
    const int sc   = t & 3;      // staging: col group 0..3
    int srg = r0 + srow; if (srg > NR - 1) srg = NR - 1;

    float acc[4][4];

    // ================= shape: 9 K-chunks (5 id + 4 ex) =================
#pragma unroll
    for (int i = 0; i < 4; i++)
#pragma unroll
        for (int j = 0; j < 4; j++) acc[i][j] = 0.f;

    for (int kc = 0; kc < 9; kc++) {
        const float* src;
        int ld, k0;
        if (kc < 5) { src = idBase; ld = 80; k0 = kc * 16; }
        else        { src = exBase; ld = 64; k0 = (kc - 5) * 16; }

        // stage A: 64 rows x 16 cols, 1 float4/thread, transposed into As
        {
            float4 v = *(const float4*)(src + (size_t)srg * ld + k0 + sc * 4);
            As[sc * 4 + 0][srow] = v.x;
            As[sc * 4 + 1][srow] = v.y;
            As[sc * 4 + 2][srow] = v.z;
            As[sc * 4 + 3][srow] = v.w;
        }
        // stage B: 16x64 floats = 256 float4; 1 per thread
        ((float4*)&Bs[0][0])[t] = ((const float4*)(ctrS + (size_t)kc * 16 * 64))[t];
        __syncthreads();

#pragma unroll
        for (int k = 0; k < 16; k++) {
            float4 a = *(const float4*)&As[k][tm * 4];
            float4 b = *(const float4*)&Bs[k][tn * 4];
            float av[4] = {a.x, a.y, a.z, a.w};
            float bv[4] = {b.x, b.y, b.z, b.w};
#pragma unroll
            for (int i = 0; i < 4; i++)
#pragma unroll
                for (int j = 0; j < 4; j++)
                    acc[i][j] += av[i] * bv[j];
        }
        __syncthreads();
    }

    // epilogue shape: += meanshape; shapeT float4 coalesced (+ shape3 scatter)
#pragma unroll
    for (int i = 0; i < 4; i++) {
        int rg = r0 + tm * 4 + i;
        if (rg < NR) {
            float ms = meanshape[rg];
            float s0 = acc[i][0] + ms, s1 = acc[i][1] + ms;
            float s2 = acc[i][2] + ms, s3 = acc[i][3] + ms;
            float4 o = {s0, s1, s2, s3};
            *(float4*)(shapeT + (size_t)rg * 64 + tn * 4) = o;
            if (write_s3) {
                int v = rg / 3;
                int c = rg - v * 3;
                float* p = shape3 + ((size_t)v * 64 + tn * 4) * 3 + c;
                p[0] = s0; p[3] = s1; p[6] = s2; p[9] = s3;
            }
        }
    }

    // ================= tex: 5 K-chunks =================
#pragma unroll
    for (int i = 0; i < 4; i++)
#pragma unroll
        for (int j = 0; j < 4; j++) acc[i][j] = 0.f;

    for (int kc = 0; kc < 5; kc++) {
        int k0 = kc * 16;
        {
            float4 v = *(const float4*)(texBase + (size_t)srg * 80 + k0 + sc * 4);
            As[sc * 4 + 0][srow] = v.x;
            As[sc * 4 + 1][srow] = v.y;
            As[sc * 4 + 2][srow] = v.z;
            As[sc * 4 + 3][srow] = v.w;
        }
        ((float4*)&Bs[0][0])[t] = ((const float4*)(ctrT + (size_t)kc * 16 * 64))[t];
        __syncthreads();

#pragma unroll
        for (int k = 0; k < 16; k++) {
            float4 a = *(const float4*)&As[k][tm * 4];
            float4 b = *(const float4*)&Bs[k][tn * 4];
            float av[4] = {a.x, a.y, a.z, a.w};
            float bv[4] = {b.x, b.y, b.z, b.w};
#pragma unroll
            for (int i = 0; i < 4; i++)
#pragma unroll
                for (int j = 0; j < 4; j++)
                    acc[i][j] += av[i] * bv[j];
        }
        __syncthreads();
    }

    const float inv255 = 1.0f / 255.0f;
    if (tex_transposed) {
#pragma unroll
        for (int i = 0; i < 4; i++) {
            int rg = r0 + tm * 4 + i;
            if (rg < NR) {
                float mt = meantex[rg];
                float4 o = {(acc[i][0] + mt) * inv255, (acc[i][1] + mt) * inv255,
                            (acc[i][2] + mt) * inv255, (acc[i][3] + mt) * inv255};
                *(float4*)(texT + (size_t)rg * 64 + tn * 4) = o;
            }
        }
    } else {
        // tiny-ws fallback: out_color [b][NR] layout (uncoalesced but correct)
#pragma unroll
        for (int i = 0; i < 4; i++) {
            int rg = r0 + tm * 4 + i;
            if (rg < NR) {
                float mt = meantex[rg];
#pragma unroll
                for (int j = 0; j < 4; j++)
                    texT[(size_t)(tn * 4 + j) * NR + rg] = (acc[i][j] + mt) * inv255;
            }
        }
    }
}

// Face normals from shape3: 3 packed float3 gathers per face.
// Covers f = 0..N_F inclusive; f==N_F is the sentinel zero row.
__global__ __launch_bounds__(256) void k_facenorm3(
    const float* __restrict__ shape3,
    const int* __restrict__ face_buf,
    float* __restrict__ fnT3)           // [(f*64+b)*3 + c]
{
    int wave = threadIdx.x >> 6;
    int b    = threadIdx.x & 63;
    int f0   = blockIdx.x * 32 + wave * 8;
#pragma unroll
    for (int fr = 0; fr < 8; fr++) {
        int f = f0 + fr;
        if (f < N_F) {
            int i0 = face_buf[f * 3 + 0];
            int i1 = face_buf[f * 3 + 1];
            int i2 = face_buf[f * 3 + 2];
            const float* p0 = shape3 + ((size_t)i0 * 64 + b) * 3;
            const float* p1 = shape3 + ((size_t)i1 * 64 + b) * 3;
            const float* p2 = shape3 + ((size_t)i2 * 64 + b) * 3;
            float p0x = p0[0], p0y = p0[1], p0z = p0[2];
            float p1x = p1[0], p1y = p1[1], p1z = p1[2];
            float p2x = p2[0], p2y = p2[1], p2z = p2[2];
            float e1x = p0x - p1x, e1y = p0y - p1y, e1z = p0z - p1z;
            float e2x = p1x - p2x, e2y = p1y - p2y, e2z = p1z - p2z;
            float ccx = e1y * e2z - e1z * e2y;
            float ccy = e1z * e2x - e1x * e2z;
            float ccz = e1x * e2y - e1y * e2x;
            float l = sqrtf(ccx * ccx + ccy * ccy + ccz * ccz);
            float inv = 1.0f / fmaxf(l, 1e-12f);
            float* o = fnT3 + ((size_t)f * 64 + b) * 3;
            o[0] = ccx * inv; o[1] = ccy * inv; o[2] = ccz * inv;
        } else if (f == N_F) {
            float* o = fnT3 + ((size_t)f * 64 + b) * 3;
            o[0] = 0.f; o[1] = 0.f; o[2] = 0.f;
        }
    }
}

// Fallback facenorm reading shapeT directly (no shape3 ws room). Writes fnT3 layout.
__global__ __launch_bounds__(256) void k_facenorm(
    const float* __restrict__ shapeT,   // [i][64]
    const int* __restrict__ face_buf,
    float* __restrict__ fnT3)
{
    int wave = threadIdx.x >> 6;
    int b    = threadIdx.x & 63;
    int f0   = blockIdx.x * 32 + wave * 8;
#pragma unroll
    for (int fr = 0; fr < 8; fr++) {
        int f = f0 + fr;
        if (f < N_F) {
            int i0 = face_buf[f * 3 + 0];
            int i1 = face_buf[f * 3 + 1];
            int i2 = face_buf[f * 3 + 2];
            float p0x = shapeT[(size_t)(3 * i0)     * 64 + b];
            float p0y = shapeT[(size_t)(3 * i0 + 1) * 64 + b];
            float p0z = shapeT[(size_t)(3 * i0 + 2) * 64 + b];
            float p1x = shapeT[(size_t)(3 * i1)     * 64 + b];
            float p1y = shapeT[(size_t)(3 * i1 + 1) * 64 + b];
            float p1z = shapeT[(size_t)(3 * i1 + 2) * 64 + b];
            float p2x = shapeT[(size_t)(3 * i2)     * 64 + b];
            float p2y = shapeT[(size_t)(3 * i2 + 1) * 64 + b];
            float p2z = shapeT[(size_t)(3 * i2 + 2) * 64 + b];
            float e1x = p0x - p1x, e1y = p0y - p1y, e1z = p0z - p1z;
            float e2x = p1x - p2x, e2y = p1y - p2y, e2z = p1z - p2z;
            float ccx = e1y * e2z - e1z * e2y;
            float ccy = e1z * e2x - e1x * e2z;
            float ccz = e1x * e2y - e1y * e2x;
            float l = sqrtf(ccx * ccx + ccy * ccy + ccz * ccz);
            float inv = 1.0f / fmaxf(l, 1e-12f);
            float* o = fnT3 + ((size_t)f * 64 + b) * 3;
            o[0] = ccx * inv; o[1] = ccy * inv; o[2] = ccz * inv;
        } else if (f == N_F) {
            float* o = fnT3 + ((size_t)f * 64 + b) * 3;
            o[0] = 0.f; o[1] = 0.f; o[2] = 0.f;
        }
    }
}

// Vertex kernel: 8 unconditional float3 fnT3 gathers per vertex (sentinel handles f==N_F).
// All point_buf / own-row loads hoisted ahead of gather consumption for MLP.
__global__ __launch_bounds__(256) void k_vertex_fn(
    const float* __restrict__ shapeT,  // [i][64]
    const float* __restrict__ texT,    // [i][64]
    const float* __restrict__ fnT3,    // [(f*64+b)*3 + c]
    const float* __restrict__ rotM, const float* __restrict__ gm,
    const float* __restrict__ coeffs,
    const int* __restrict__ point_buf,
    float* __restrict__ out_vertex, float* __restrict__ out_color)
{
    __shared__ float sh[64 * 49];   // [b][48] padded to 49
    int wave = threadIdx.x >> 6;
    int b    = threadIdx.x & 63;
    int v0   = blockIdx.x * 16;
    int nvalid = N_V - v0; if (nvalid > 16) nvalid = 16;
    int kmax = 3 * nvalid;

    float m0 = rotM[b * 9 + 0], m1 = rotM[b * 9 + 1], m2 = rotM[b * 9 + 2];
    float m3 = rotM[b * 9 + 3], m4 = rotM[b * 9 + 4], m5 = rotM[b * 9 + 5];
    float m6 = rotM[b * 9 + 6], m7 = rotM[b * 9 + 7], m8 = rotM[b * 9 + 8];
    float tx = coeffs[b * 257 + 254], ty = coeffs[b * 257 + 255], tz = coeffs[b * 257 + 256];
    float g[27];
#pragma unroll
    for (int k = 0; k < 27; k++) g[k] = gm[b * 27 + k];

    const float A0C0 = 0.8862269254527580f;
    const float A1C1 = 1.7724538509055159f;
    const float A2C2 = 2.4270323912f;
    const float C6   = 0.7006239022f;
    const float C8   = 1.2135161956f;

    // ---- hoisted loads: point_buf indices + own shape/tex rows for all 4 vertices ----
    int pf[4][8];
    float sxv[4], syv[4], szv[4];
    float t0v[4], t1v[4], t2v[4];
#pragma unroll
    for (int vr = 0; vr < 4; vr++) {
        int v = v0 + wave * 4 + vr;
        int vc = (v < N_V) ? v : (N_V - 1);
#pragma unroll
        for (int k = 0; k < 8; k++) pf[vr][k] = point_buf[vc * 8 + k];
        sxv[vr] = shapeT[(size_t)(3 * vc)     * 64 + b];
        syv[vr] = shapeT[(size_t)(3 * vc + 1) * 64 + b];
        szv[vr] = shapeT[(size_t)(3 * vc + 2) * 64 + b];
        t0v[vr] = texT[(size_t)(3 * vc)     * 64 + b];
        t1v[vr] = texT[(size_t)(3 * vc + 1) * 64 + b];
        t2v[vr] = texT[(size_t)(3 * vc + 2) * 64 + b];
    }

    float vert[4][3];
    float col[4][3];

#pragma unroll
    for (int vr = 0; vr < 4; vr++) {
        // gather 8 float3 normals (unconditional; f==N_F is zero sentinel)
        float fx[8], fy[8], fz[8];
#pragma unroll
        for (int k = 0; k < 8; k++) {
            const float* fp = fnT3 + ((size_t)pf[vr][k] * 64 + b) * 3;
            fx[k] = fp[0]; fy[k] = fp[1]; fz[k] = fp[2];
        }

        float vx = m0 * sxv[vr] + m1 * syv[vr] + m2 * szv[vr] + tx;
        float vy = m3 * sxv[vr] + m4 * syv[vr] + m5 * szv[vr] + ty;
        float vz = m6 * sxv[vr] + m7 * syv[vr] + m8 * szv[vr] + tz;
        vert[vr][0] = vx; vert[vr][1] = vy; vert[vr][2] = 10.0f - vz;

        float nx = 0.f, ny = 0.f, nz = 0.f;
#pragma unroll
        for (int k = 0; k < 8; k++) { nx += fx[k]; ny += fy[k]; nz += fz[k]; }
        float l = sqrtf(nx * nx + ny * ny + nz * nz);
        float inv = 1.0f / fmaxf(l, 1e-12f);
        nx *= inv; ny *= inv; nz *= inv;

        float rx = m0 * nx + m1 * ny + m2 * nz;
        float ry = m3 * nx + m4 * ny + m5 * nz;
        float rz = m6 * nx + m7 * ny + m8 * nz;

        float Y0 = A0C0;
        float Y1 = -A1C1 * ry;
        float Y2 =  A1C1 * rz;
        float Y3 = -A1C1 * rx;
        float Y4 =  A2C2 * rx * ry;
        float Y5 = -A2C2 * ry * rz;
        float Y6 =  C6 * (3.f * rz * rz - 1.f);
        float Y7 = -A2C2 * rx * rz;
        float Y8 =  C8 * (rx * rx - ry * ry);

        float tex3[3] = {t0v[vr], t1v[vr], t2v[vr]};
#pragma unroll
        for (int c = 0; c < 3; c++) {
            float rgb = Y0 * g[0 + c] + Y1 * g[3 + c] + Y2 * g[6 + c] + Y3 * g[9 + c] +
                        Y4 * g[12 + c] + Y5 * g[15 + c] + Y6 * g[18 + c] + Y7 * g[21 + c] +
                        Y8 * g[24 + c];
            col[vr][c] = rgb * tex3[c];
        }
    }

    // ---- stage + flush vertex ----
#pragma unroll
    for (int vr = 0; vr < 4; vr++)
#pragma unroll
        for (int c = 0; c < 3; c++)
            sh[b * 49 + (wave * 4 + vr) * 3 + c] = vert[vr][c];
    __syncthreads();
#pragma unroll 4
    for (int it = 0; it < 12; it++) {
        int f = it * 256 + threadIdx.x;
        int bb = f / 48, k = f - bb * 48;
        if (k < kmax)
            __builtin_nontemporal_store(sh[bb * 49 + k],
                                        out_vertex + (size_t)bb * NR + 3 * (size_t)v0 + k);
    }
    __syncthreads();

    // ---- stage + flush color ----
#pragma unroll
    for (int vr = 0; vr < 4; vr++)
#pragma unroll
        for (int c = 0; c < 3; c++)
            sh[b * 49 + (wave * 4 + vr) * 3 + c] = col[vr][c];
    __syncthreads();
#pragma unroll 4
    for (int it = 0; it < 12; it++) {
        int f = it * 256 + threadIdx.x;
        int bb = f / 48, k = f - bb * 48;
        if (k < kmax)
            __builtin_nontemporal_store(sh[bb * 49 + k],
                                        out_color + (size_t)bb * NR + 3 * (size_t)v0 + k);
    }
}

// FALLBACK (ws too small for fnT3): original fused kernel, unchanged.
__global__ __launch_bounds__(256) void k_vertex(
    const float* __restrict__ shapeT,
    const float* __restrict__ texT,
    const float* __restrict__ rotM, const float* __restrict__ gm,
    const float* __restrict__ coeffs,
    const int* __restrict__ point_buf, const int* __restrict__ face_buf,
    float* __restrict__ out_vertex, float* __restrict__ out_color,
    int tex_in_out)
{
    __shared__ float sh[64 * 97];
    int wave = threadIdx.x >> 6;
    int b    = threadIdx.x & 63;
    int v0   = blockIdx.x * 32;
    int nvalid = N_V - v0; if (nvalid > 32) nvalid = 32;
    int kmax = 3 * nvalid;

    float m0 = rotM[b * 9 + 0], m1 = rotM[b * 9 + 1], m2 = rotM[b * 9 + 2];
    float m3 = rotM[b * 9 + 3], m4 = rotM[b * 9 + 4], m5 = rotM[b * 9 + 5];
    float m6 = rotM[b * 9 + 6], m7 = rotM[b * 9 + 7], m8 = rotM[b * 9 + 8];
    float tx = coeffs[b * 257 + 254], ty = coeffs[b * 257 + 255], tz = coeffs[b * 257 + 256];
    float g[27];
#pragma unroll
    for (int k = 0; k < 27; k++) g[k] = gm[b * 27 + k];

    const float A0C0 = 0.8862269254527580f;
    const float A1C1 = 1.7724538509055159f;
    const float A2C2 = 2.4270323912f;
    const float C6   = 0.7006239022f;
    const float C8   = 1.2135161956f;

    float vert[8][3];
    float col[8][3];

#pragma unroll
    for (int vr = 0; vr < 8; vr++) {
        int v = v0 + wave * 8 + vr;
        bool valid = (v < N_V);
        int vc = valid ? v : (N_V - 1);

        float sx0 = shapeT[(size_t)(3 * vc)     * 64 + b];
        float sy0 = shapeT[(size_t)(3 * vc + 1) * 64 + b];
        float sz0 = shapeT[(size_t)(3 * vc + 2) * 64 + b];

        float vx = m0 * sx0 + m1 * sy0 + m2 * sz0 + tx;
        float vy = m3 * sx0 + m4 * sy0 + m5 * sz0 + ty;
        float vz = m6 * sx0 + m7 * sy0 + m8 * sz0 + tz;
        vert[vr][0] = vx; vert[vr][1] = vy; vert[vr][2] = 10.0f - vz;

        float nx = 0.f, ny = 0.f, nz = 0.f;
#pragma unroll
        for (int k = 0; k < 8; k++) {
            int f = point_buf[vc * 8 + k];
            if (f < N_F) {
                int i0 = face_buf[f * 3], i1 = face_buf[f * 3 + 1], i2 = face_buf[f * 3 + 2];
                float p0x = shapeT[(size_t)(3 * i0)     * 64 + b];
                float p0y = shapeT[(size_t)(3 * i0 + 1) * 64 + b];
                float p0z = shapeT[(size_t)(3 * i0 + 2) * 64 + b];
                float p1x = shapeT[(size_t)(3 * i1)     * 64 + b];
                float p1y = shapeT[(size_t)(3 * i1 + 1) * 64 + b];
                float p1z = shapeT[(size_t)(3 * i1 + 2) * 64 + b];
                float p2x = shapeT[(size_t)(3 * i2)     * 64 + b];
                float p2y = shapeT[(size_t)(3 * i2 + 1) * 64 + b];
                float p2z = shapeT[(size_t)(3 * i2 + 2) * 64 + b];
                float e1x = p0x - p1x, e1y = p0y - p1y, e1z = p0z - p1z;
                float e2x = p1x - p2x, e2y = p1y - p2y, e2z = p1z - p2z;
                float ccx = e1y * e2z - e1z * e2y;
                float ccy = e1z * e2x - e1x * e2z;
                float ccz = e1x * e2y - e1y * e2x;
                float l = sqrtf(ccx * ccx + ccy * ccy + ccz * ccz);
                float inv = 1.0f / fmaxf(l, 1e-12f);
                nx += ccx * inv; ny += ccy * inv; nz += ccz * inv;
            }
        }
        float l = sqrtf(nx * nx + ny * ny + nz * nz);
        float inv = 1.0f / fmaxf(l, 1e-12f);
        nx *= inv; ny *= inv; nz *= inv;

        float rx = m0 * nx + m1 * ny + m2 * nz;
        float ry = m3 * nx + m4 * ny + m5 * nz;
        float rz = m6 * nx + m7 * ny + m8 * nz;

        float Y0 = A0C0;
        float Y1 = -A1C1 * ry;
        float Y2 =  A1C1 * rz;
        float Y3 = -A1C1 * rx;
        float Y4 =  A2C2 * rx * ry;
        float Y5 = -A2C2 * ry * rz;
        float Y6 =  C6 * (3.f * rz * rz - 1.f);
        float Y7 = -A2C2 * rx * rz;
        float Y8 =  C8 * (rx * rx - ry * ry);

        float t0, t1, t2;
        if (tex_in_out) {
            size_t ob = (size_t)b * NR + 3 * (size_t)vc;
            t0 = out_color[ob]; t1 = out_color[ob + 1]; t2 = out_color[ob + 2];
        } else {
            t0 = texT[(size_t)(3 * vc)     * 64 + b];
            t1 = texT[(size_t)(3 * vc + 1) * 64 + b];
            t2 = texT[(size_t)(3 * vc + 2) * 64 + b];
        }
        float tex3[3] = {t0, t1, t2};
#pragma unroll
        for (int c = 0; c < 3; c++) {
            float rgb = Y0 * g[0 + c] + Y1 * g[3 + c] + Y2 * g[6 + c] + Y3 * g[9 + c] +
                        Y4 * g[12 + c] + Y5 * g[15 + c] + Y6 * g[18 + c] + Y7 * g[21 + c] +
                        Y8 * g[24 + c];
            col[vr][c] = rgb * tex3[c];
        }
    }

#pragma unroll
    for (int vr = 0; vr < 8; vr++)
#pragma unroll
        for (int c = 0; c < 3; c++)
            sh[b * 97 + (wave * 8 + vr) * 3 + c] = vert[vr][c];
    __syncthreads();
#pragma unroll 4
    for (int it = 0; it < 24; it++) {
        int f = it * 256 + threadIdx.x;
        int bb = f / 96, k = f - bb * 96;
        if (k < kmax)
            __builtin_nontemporal_store(sh[bb * 97 + k],
                                        out_vertex + (size_t)bb * NR + 3 * (size_t)v0 + k);
    }
    __syncthreads();

#pragma unroll
    for (int vr = 0; vr < 8; vr++)
#pragma unroll
        for (int c = 0; c < 3; c++)
            sh[b * 97 + (wave * 8 + vr) * 3 + c] = col[vr][c];
    __syncthreads();
#pragma unroll 4
    for (int it = 0; it < 24; it++) {
        int f = it * 256 + threadIdx.x;
        int bb = f / 96, k = f - bb * 96;
        if (k < kmax)
            __builtin_nontemporal_store(sh[bb * 97 + k],
                                        out_color + (size_t)bb * NR + 3 * (size_t)v0 + k);
    }
}

// grid = 68 blocks of 64 (lane = batch); recompute transform from shapeT
__global__ __launch_bounds__(64) void k_landmark(
    const float* __restrict__ shapeT, const int* __restrict__ keypoints,
    const float* __restrict__ rotM, const float* __restrict__ coeffs,
    const float* __restrict__ P,
    float* __restrict__ out_lm)
{
    int l = blockIdx.x;
    int b = threadIdx.x;
    int kp = keypoints[l];

    float m0 = rotM[b * 9 + 0], m1 = rotM[b * 9 + 1], m2 = rotM[b * 9 + 2];
    float m3 = rotM[b * 9 + 3], m4 = rotM[b * 9 + 4], m5 = rotM[b * 9 + 5];
    float m6 = rotM[b * 9 + 6], m7 = rotM[b * 9 + 7], m8 = rotM[b * 9 + 8];
    float tx = coeffs[b * 257 + 254], ty = coeffs[b * 257 + 255], tz = coeffs[b * 257 + 256];

    float sx0 = shapeT[(size_t)(3 * kp)     * 64 + b];
    float sy0 = shapeT[(size_t)(3 * kp + 1) * 64 + b];
    float sz0 = shapeT[(size_t)(3 * kp + 2) * 64 + b];

    float x = m0 * sx0 + m1 * sy0 + m2 * sz0 + tx;
    float y = m3 * sx0 + m4 * sy0 + m5 * sz0 + ty;
    float z = 10.0f - (m6 * sx0 + m7 * sy0 + m8 * sz0 + tz);

    float p0 = x * P[0] + y * P[3] + z * P[6];
    float p1 = x * P[1] + y * P[4] + z * P[7];
    float p2 = x * P[2] + y * P[5] + z * P[8];

    size_t o = ((size_t)b * 68 + l) * 2;
    out_lm[o]     = p0 / p2;
    out_lm[o + 1] = p1 / p2;
}

extern "C" void kernel_launch(void* const* d_in, const int* in_sizes, int n_in,
                              void* d_out, int out_size, void* d_ws, size_t ws_size,
                              hipStream_t stream) {
    const float* coeffs    = (const float*)d_in[0];
    const float* meanshape = (const float*)d_in[1];
    const float* idBase    = (const float*)d_in[2];
    const float* exBase    = (const float*)d_in[3];
    const float* meantex   = (const float*)d_in[4];
    const float* texBase   = (const float*)d_in[5];
    const float* persc     = (const float*)d_in[6];
    const float* init_lit  = (const float*)d_in[7];
    const int*   point_buf = (const int*)d_in[8];
    const int*   face_buf  = (const int*)d_in[9];
    const int*   keypoints = (const int*)d_in[10];

    float* ws = (float*)d_ws;
    float* rotM = ws + WS_ROT;
    float* gm   = ws + WS_GM;
    float* ctrS = ws + WS_CTRS;
    float* ctrT = ws + WS_CTRT;
    float* shapeT = ws + WS_SHAPET;

    float* out_vertex = (float*)d_out;
    float* out_color  = out_vertex + (size_t)NB * NR;
    float* out_lm     = out_color  + (size_t)NB * NR;

    size_t NRx64   = (size_t)NR * 64;
    size_t fn3_len = (size_t)(N_F + 1) * 64 * 3;
    size_t sh3_len = (size_t)N_V * 64 * 3;

    size_t need_tex = ((size_t)WS_SHAPET + 2 * NRx64) * sizeof(float);
    size_t need_fn  = need_tex + fn3_len * sizeof(float);
    size_t need_s3  = need_fn + sh3_len * sizeof(float);

    int tex_transposed = (ws_size >= need_tex) ? 1 : 0;
    int use_fn         = (ws_size >= need_fn) ? 1 : 0;
    int use_s3         = (ws_size >= need_s3) ? 1 : 0;

    float* texT   = tex_transposed ? (shapeT + NRx64) : out_color;
    float* fnT3   = shapeT + 2 * NRx64;
    float* shape3 = fnT3 + fn3_len;

    k_setup_rot<<<1, 64, 0, stream>>>(coeffs, init_lit, rotM, gm);
    k_transpose<<<224, 64, 0, stream>>>(coeffs, ctrS, ctrT);

    int gb = (NR + 63) / 64;
    k_gemm_tile<<<gb, 256, 0, stream>>>(idBase, exBase, texBase, meanshape,
                                        meantex, ctrS, ctrT, shapeT, texT,
                                        shape3, use_s3, tex_transposed);

    if (use_fn) {
        int fb = (N_F + 1 + 31) / 32;
        if (use_s3) {
            k_facenorm3<<<fb, 256, 0, stream>>>(shape3, face_buf, fnT3);
        } else {
            k_facenorm<<<fb, 256, 0, stream>>>(shapeT, face_buf, fnT3);
        }
        int vb = (N_V + 15) / 16;
        k_vertex_fn<<<vb, 256, 0, stream>>>(shapeT, texT, fnT3, rotM, gm, coeffs,
                                            point_buf, out_vertex, out_color);
    } else {
        int vb = (N_V + 31) / 32;
        k_vertex<<<vb, 256, 0, stream>>>(shapeT, tex_transposed ? texT : nullptr,
                                         rotM, gm, coeffs, point_buf, face_buf,
                                         out_vertex, out_color,
                                         tex_transposed ? 0 : 1);
    }

    k_landmark<<<68, 64, 0, stream>>>(shapeT, keypoints, rotM, coeffs, persc, out_lm);
}

// Round 12
// 278.497 us; speedup vs baseline: 1.0758x; 1.0249x over previous
//
#include <hip/hip_runtime.h>

#define N_V 35709
#define N_F 70789
#define NR  (3*N_V)   // 107127
#define NB  64

// ws layout (floats):
//   rotM  : NB*9   = 576    @ 0
//   gm    : NB*27  = 1728   @ 576
//   ctrS  : 144*NB = 9216   @ 2304   (id+ex coeffs, [j][b])
//   ctrT  : 80*NB  = 5120   @ 11520  (tex coeffs, [j][b])
//   shapeT: NR*64          @ 16640   (fallback path only)
//   texT  : NR*64          @ +NR*64
//   fnT3  : (N_F+1)*64*3   @ +NR*64    (unit face normals, sentinel 0 at f=N_F)
//   shape3: N_V*64*3       @ +fnT3     (shape packed float3 per (v,b); fast path)
#define WS_ROT    0
#define WS_GM     576
#define WS_CTRS   2304
#define WS_CTRT   11520
#define WS_SHAPET 16640

__global__ __launch_bounds__(64) void k_setup_rot(
    const float* __restrict__ coeffs, const float* __restrict__ init_lit,
    float* __restrict__ rotM, float* __restrict__ gm)
{
    int b = threadIdx.x;
    const float* cb = coeffs + b * 257;

    float ax = cb[224], ay = cb[225], az = cb[226];
    float cx = cosf(ax), sx = sinf(ax);
    float cy = cosf(ay), sy = sinf(ay);
    float cz = cosf(az), sz = sinf(az);
    float m[9];
    m[0] = cz * cy;
    m[1] = cz * sy * sx - sz * cx;
    m[2] = sz * sx + cz * sy * cx;
    m[3] = sz * cy;
    m[4] = cz * cx + sz * sy * sx;
    m[5] = sz * sy * cx - cz * sx;
    m[6] = -sy;
    m[7] = cy * sx;
    m[8] = cy * cx;
#pragma unroll
    for (int k = 0; k < 9; k++) rotM[b * 9 + k] = m[k];

#pragma unroll
    for (int k = 0; k < 9; k++) {
        float il = init_lit[k];
#pragma unroll
        for (int c = 0; c < 3; c++)
            gm[b * 27 + k * 3 + c] = cb[227 + c * 9 + k] + il;
    }
}

// grid = 224 blocks of 64: block j transposes coeff column j into [j][b]
__global__ __launch_bounds__(64) void k_transpose(
    const float* __restrict__ coeffs,
    float* __restrict__ ctrS, float* __restrict__ ctrT)
{
    int j = blockIdx.x;
    int b = threadIdx.x;
    float v = coeffs[b * 257 + j];
    if (j < 144) ctrS[j * 64 + b] = v;
    else         ctrT[(j - 144) * 64 + b] = v;
}

// LDS-tiled register-blocked GEMM — round-7 verified single-buffered body.
// Fast path (write_s3): shape epilogue stages the 64x64 tile in LDS (two 32-row
// halves, aliasing As/Bs) and drains as consecutive-dword COALESCED stores into
// packed shape3 (fused repack, written once). Fallback: shapeT float4 stores.
__global__ __launch_bounds__(256) void k_gemm_tile(
    const float* __restrict__ idBase, const float* __restrict__ exBase,
    const float* __restrict__ texBase, const float* __restrict__ meanshape,
    const float* __restrict__ meantex,
    const float* __restrict__ ctrS, const float* __restrict__ ctrT,
    float* __restrict__ shapeT,      // [i][64], fallback only
    float* __restrict__ texT,        // [i][64] if transposed, else out_color [b][NR]
    float* __restrict__ shape3,      // [(v*64+b)*3+c], fast path
    int write_s3, int tex_transposed)
{
    __shared__ __align__(16) float smem[2112];   // 8448 B, same as round-7
    float (*As)[68] = (float (*)[68])smem;        // 16x68 = 1088 floats
    float (*Bs)[64] = (float (*)[64])(smem + 1088); // 16x64 = 1024 floats
    float* epi = smem;                            // epilogue: 32x65 = 2080 floats

    const int t  = threadIdx.x;
    const int tn = t & 15;       // batch group
    const int tm = t >> 4;       // row group (0..15)
    const int r0 = blockIdx.x * 64;

    const int srow = t >> 2;     // staging: row 0..63
    const int sc   = t & 3;      // staging: col group 0..3
    int srg = r0 + srow; if (srg > NR - 1) srg = NR - 1;

    float acc[4][4];

    // ================= shape: 9 K-chunks (5 id + 4 ex) =================
#pragma unroll
    for (int i = 0; i < 4; i++)
#pragma unroll
        for (int j = 0; j < 4; j++) acc[i][j] = 0.f;

    for (int kc = 0; kc < 9; kc++) {
        const float* src;
        int ld, k0;
        if (kc < 5) { src = idBase; ld = 80; k0 = kc * 16; }
        else        { src = exBase; ld = 64; k0 = (kc - 5) * 16; }

        {
            float4 v = *(const float4*)(src + (size_t)srg * ld + k0 + sc * 4);
            As[sc * 4 + 0][srow] = v.x;
            As[sc * 4 + 1][srow] = v.y;
            As[sc * 4 + 2][srow] = v.z;
            As[sc * 4 + 3][srow] = v.w;
        }
        ((float4*)&Bs[0][0])[t] = ((const float4*)(ctrS + (size_t)kc * 16 * 64))[t];
        __syncthreads();

#pragma unroll
        for (int k = 0; k < 16; k++) {
            float4 a = *(const float4*)&As[k][tm * 4];
            float4 b = *(const float4*)&Bs[k][tn * 4];
            float av[4] = {a.x, a.y, a.z, a.w};
            float bv[4] = {b.x, b.y, b.z, b.w};
#pragma unroll
            for (int i = 0; i < 4; i++)
#pragma unroll
                for (int j = 0; j < 4; j++)
                    acc[i][j] += av[i] * bv[j];
        }
        __syncthreads();
    }

    // meanshape per owned row
    float msv[4];
#pragma unroll
    for (int i = 0; i < 4; i++) {
        int rg = r0 + tm * 4 + i;
        msv[i] = meanshape[(rg < NR) ? rg : (NR - 1)];
    }

    if (write_s3) {
        // coalesced shape3 epilogue: two 32-row halves via LDS transpose
#pragma unroll
        for (int h = 0; h < 2; h++) {
            if ((tm >> 3) == h) {
                int lr0 = (tm & 7) * 4;
#pragma unroll
                for (int i = 0; i < 4; i++)
#pragma unroll
                    for (int j = 0; j < 4; j++)
                        epi[(lr0 + i) * 65 + tn * 4 + j] = acc[i][j] + msv[i];
            }
            __syncthreads();
            int R0   = r0 + h * 32;
            int Rend = R0 + 32; if (Rend > NR) Rend = NR;
            if (R0 < NR) {
                int vlo  = R0 / 3;
                int vhi  = (Rend - 1) / 3;
                int base = vlo * 192;
                int span = (vhi + 1) * 192 - base;
                for (int q = t; q < span; q += 256) {
                    int addr = base + q;
                    int v    = addr / 192;
                    int rem  = addr - v * 192;
                    int b    = rem / 3;
                    int c    = rem - b * 3;
                    int r    = 3 * v + c;
                    if (r >= R0 && r < Rend)
                        shape3[addr] = epi[(r - R0) * 65 + b];
                }
            }
            __syncthreads();
        }
    } else {
#pragma unroll
        for (int i = 0; i < 4; i++) {
            int rg = r0 + tm * 4 + i;
            if (rg < NR) {
                float4 o = {acc[i][0] + msv[i], acc[i][1] + msv[i],
                            acc[i][2] + msv[i], acc[i][3] + msv[i]};
                *(float4*)(shapeT + (size_t)rg * 64 + tn * 4) = o;
            }
        }
    }

    // ================= tex: 5 K-chunks =================
#pragma unroll
    for (int i = 0; i < 4; i++)
#pragma unroll
        for (int j = 0; j < 4; j++) acc[i][j] = 0.f;

    for (int kc = 0; kc < 5; kc++) {
        int k0 = kc * 16;
        {
            float4 v = *(const float4*)(texBase + (size_t)srg * 80 + k0 + sc * 4);
            As[sc * 4 + 0][srow] = v.x;
            As[sc * 4 + 1][srow] = v.y;
            As[sc * 4 + 2][srow] = v.z;
            As[sc * 4 + 3][srow] = v.w;
        }
        ((float4*)&Bs[0][0])[t] = ((const float4*)(ctrT + (size_t)kc * 16 * 64))[t];
        __syncthreads();

#pragma unroll
        for (int k = 0; k < 16; k++) {
            float4 a = *(const float4*)&As[k][tm * 4];
            float4 b = *(const float4*)&Bs[k][tn * 4];
            float av[4] = {a.x, a.y, a.z, a.w};
            float bv[4] = {b.x, b.y, b.z, b.w};
#pragma unroll
            for (int i = 0; i < 4; i++)
#pragma unroll
                for (int j = 0; j < 4; j++)
                    acc[i][j] += av[i] * bv[j];
        }
        __syncthreads();
    }

    const float inv255 = 1.0f / 255.0f;
    if (tex_transposed) {
#pragma unroll
        for (int i = 0; i < 4; i++) {
            int rg = r0 + tm * 4 + i;
            if (rg < NR) {
                float mt = meantex[rg];
                float4 o = {(acc[i][0] + mt) * inv255, (acc[i][1] + mt) * inv255,
                            (acc[i][2] + mt) * inv255, (acc[i][3] + mt) * inv255};
                *(float4*)(texT + (size_t)rg * 64 + tn * 4) = o;
            }
        }
    } else {
        // tiny-ws fallback: out_color [b][NR] layout (uncoalesced but correct)
#pragma unroll
        for (int i = 0; i < 4; i++) {
            int rg = r0 + tm * 4 + i;
            if (rg < NR) {
                float mt = meantex[rg];
#pragma unroll
                for (int j = 0; j < 4; j++)
                    texT[(size_t)(tn * 4 + j) * NR + rg] = (acc[i][j] + mt) * inv255;
            }
        }
    }
}

// Face normals from shape3: 3 packed float3 gathers per face.
// Covers f = 0..N_F inclusive; f==N_F is the sentinel zero row.
__global__ __launch_bounds__(256) void k_facenorm3(
    const float* __restrict__ shape3,
    const int* __restrict__ face_buf,
    float* __restrict__ fnT3)           // [(f*64+b)*3 + c]
{
    int wave = threadIdx.x >> 6;
    int b    = threadIdx.x & 63;
    int f0   = blockIdx.x * 32 + wave * 8;
#pragma unroll
    for (int fr = 0; fr < 8; fr++) {
        int f = f0 + fr;
        if (f < N_F) {
            int i0 = face_buf[f * 3 + 0];
            int i1 = face_buf[f * 3 + 1];
            int i2 = face_buf[f * 3 + 2];
            const float* p0 = shape3 + ((size_t)i0 * 64 + b) * 3;
            const float* p1 = shape3 + ((size_t)i1 * 64 + b) * 3;
            const float* p2 = shape3 + ((size_t)i2 * 64 + b) * 3;
            float p0x = p0[0], p0y = p0[1], p0z = p0[2];
            float p1x = p1[0], p1y = p1[1], p1z = p1[2];
            float p2x = p2[0], p2y = p2[1], p2z = p2[2];
            float e1x = p0x - p1x, e1y = p0y - p1y, e1z = p0z - p1z;
            float e2x = p1x - p2x, e2y = p1y - p2y, e2z = p1z - p2z;
            float ccx = e1y * e2z - e1z * e2y;
            float ccy = e1z * e2x - e1x * e2z;
            float ccz = e1x * e2y - e1y * e2x;
            float l = sqrtf(ccx * ccx + ccy * ccy + ccz * ccz);
            float inv = 1.0f / fmaxf(l, 1e-12f);
            float* o = fnT3 + ((size_t)f * 64 + b) * 3;
            o[0] = ccx * inv; o[1] = ccy * inv; o[2] = ccz * inv;
        } else if (f == N_F) {
            float* o = fnT3 + ((size_t)f * 64 + b) * 3;
            o[0] = 0.f; o[1] = 0.f; o[2] = 0.f;
        }
    }
}

// Fallback facenorm reading shapeT directly (no shape3 ws room). Writes fnT3 layout.
__global__ __launch_bounds__(256) void k_facenorm(
    const float* __restrict__ shapeT,   // [i][64]
    const int* __restrict__ face_buf,
    float* __restrict__ fnT3)
{
    int wave = threadIdx.x >> 6;
    int b    = threadIdx.x & 63;
    int f0   = blockIdx.x * 32 + wave * 8;
#pragma unroll
    for (int fr = 0; fr < 8; fr++) {
        int f = f0 + fr;
        if (f < N_F) {
            int i0 = face_buf[f * 3 + 0];
            int i1 = face_buf[f * 3 + 1];
            int i2 = face_buf[f * 3 + 2];
            float p0x = shapeT[(size_t)(3 * i0)     * 64 + b];
            float p0y = shapeT[(size_t)(3 * i0 + 1) * 64 + b];
            float p0z = shapeT[(size_t)(3 * i0 + 2) * 64 + b];
            float p1x = shapeT[(size_t)(3 * i1)     * 64 + b];
            float p1y = shapeT[(size_t)(3 * i1 + 1) * 64 + b];
            float p1z = shapeT[(size_t)(3 * i1 + 2) * 64 + b];
            float p2x = shapeT[(size_t)(3 * i2)     * 64 + b];
            float p2y = shapeT[(size_t)(3 * i2 + 1) * 64 + b];
            float p2z = shapeT[(size_t)(3 * i2 + 2) * 64 + b];
            float e1x = p0x - p1x, e1y = p0y - p1y, e1z = p0z - p1z;
            float e2x = p1x - p2x, e2y = p1y - p2y, e2z = p1z - p2z;
            float ccx = e1y * e2z - e1z * e2y;
            float ccy = e1z * e2x - e1x * e2z;
            float ccz = e1x * e2y - e1y * e2x;
            float l = sqrtf(ccx * ccx + ccy * ccy + ccz * ccz);
            float inv = 1.0f / fmaxf(l, 1e-12f);
            float* o = fnT3 + ((size_t)f * 64 + b) * 3;
            o[0] = ccx * inv; o[1] = ccy * inv; o[2] = ccz * inv;
        } else if (f == N_F) {
            float* o = fnT3 + ((size_t)f * 64 + b) * 3;
            o[0] = 0.f; o[1] = 0.f; o[2] = 0.f;
        }
    }
}

// Vertex kernel: 8 unconditional float3 fnT3 gathers per vertex.
// packed=1: own-vertex shape read is one dwordx3 from shape3; else shapeT rows.
__global__ __launch_bounds__(256) void k_vertex_fn(
    const float* __restrict__ shp,     // shape3 (packed) or shapeT
    const float* __restrict__ texT,    // [i][64]
    const float* __restrict__ fnT3,    // [(f*64+b)*3 + c]
    const float* __restrict__ rotM, const float* __restrict__ gm,
    const float* __restrict__ coeffs,
    const int* __restrict__ point_buf,
    float* __restrict__ out_vertex, float* __restrict__ out_color,
    int packed)
{
    __shared__ float sh[64 * 49];   // [b][48] padded to 49
    int wave = threadIdx.x >> 6;
    int b    = threadIdx.x & 63;
    int v0   = blockIdx.x * 16;
    int nvalid = N_V - v0; if (nvalid > 16) nvalid = 16;
    int kmax = 3 * nvalid;

    float m0 = rotM[b * 9 + 0], m1 = rotM[b * 9 + 1], m2 = rotM[b * 9 + 2];
    float m3 = rotM[b * 9 + 3], m4 = rotM[b * 9 + 4], m5 = rotM[b * 9 + 5];
    float m6 = rotM[b * 9 + 6], m7 = rotM[b * 9 + 7], m8 = rotM[b * 9 + 8];
    float tx = coeffs[b * 257 + 254], ty = coeffs[b * 257 + 255], tz = coeffs[b * 257 + 256];
    float g[27];
#pragma unroll
    for (int k = 0; k < 27; k++) g[k] = gm[b * 27 + k];

    const float A0C0 = 0.8862269254527580f;
    const float A1C1 = 1.7724538509055159f;
    const float A2C2 = 2.4270323912f;
    const float C6   = 0.7006239022f;
    const float C8   = 1.2135161956f;

    // ---- hoisted loads ----
    int pf[4][8];
    float sxv[4], syv[4], szv[4];
    float t0v[4], t1v[4], t2v[4];
#pragma unroll
    for (int vr = 0; vr < 4; vr++) {
        int v = v0 + wave * 4 + vr;
        int vc = (v < N_V) ? v : (N_V - 1);
#pragma unroll
        for (int k = 0; k < 8; k++) pf[vr][k] = point_buf[vc * 8 + k];
        if (packed) {
            const float* sp = shp + ((size_t)vc * 64 + b) * 3;
            sxv[vr] = sp[0]; syv[vr] = sp[1]; szv[vr] = sp[2];
        } else {
            sxv[vr] = shp[(size_t)(3 * vc)     * 64 + b];
            syv[vr] = shp[(size_t)(3 * vc + 1) * 64 + b];
            szv[vr] = shp[(size_t)(3 * vc + 2) * 64 + b];
        }
        t0v[vr] = texT[(size_t)(3 * vc)     * 64 + b];
        t1v[vr] = texT[(size_t)(3 * vc + 1) * 64 + b];
        t2v[vr] = texT[(size_t)(3 * vc + 2) * 64 + b];
    }

    float vert[4][3];
    float col[4][3];

#pragma unroll
    for (int vr = 0; vr < 4; vr++) {
        float fx[8], fy[8], fz[8];
#pragma unroll
        for (int k = 0; k < 8; k++) {
            const float* fp = fnT3 + ((size_t)pf[vr][k] * 64 + b) * 3;
            fx[k] = fp[0]; fy[k] = fp[1]; fz[k] = fp[2];
        }

        float vx = m0 * sxv[vr] + m1 * syv[vr] + m2 * szv[vr] + tx;
        float vy = m3 * sxv[vr] + m4 * syv[vr] + m5 * szv[vr] + ty;
        float vz = m6 * sxv[vr] + m7 * syv[vr] + m8 * szv[vr] + tz;
        vert[vr][0] = vx; vert[vr][1] = vy; vert[vr][2] = 10.0f - vz;

        float nx = 0.f, ny = 0.f, nz = 0.f;
#pragma unroll
        for (int k = 0; k < 8; k++) { nx += fx[k]; ny += fy[k]; nz += fz[k]; }
        float l = sqrtf(nx * nx + ny * ny + nz * nz);
        float inv = 1.0f / fmaxf(l, 1e-12f);
        nx *= inv; ny *= inv; nz *= inv;

        float rx = m0 * nx + m1 * ny + m2 * nz;
        float ry = m3 * nx + m4 * ny + m5 * nz;
        float rz = m6 * nx + m7 * ny + m8 * nz;

        float Y0 = A0C0;
        float Y1 = -A1C1 * ry;
        float Y2 =  A1C1 * rz;
        float Y3 = -A1C1 * rx;
        float Y4 =  A2C2 * rx * ry;
        float Y5 = -A2C2 * ry * rz;
        float Y6 =  C6 * (3.f * rz * rz - 1.f);
        float Y7 = -A2C2 * rx * rz;
        float Y8 =  C8 * (rx * rx - ry * ry);

        float tex3[3] = {t0v[vr], t1v[vr], t2v[vr]};
#pragma unroll
        for (int c = 0; c < 3; c++) {
            float rgb = Y0 * g[0 + c] + Y1 * g[3 + c] + Y2 * g[6 + c] + Y3 * g[9 + c] +
                        Y4 * g[12 + c] + Y5 * g[15 + c] + Y6 * g[18 + c] + Y7 * g[21 + c] +
                        Y8 * g[24 + c];
            col[vr][c] = rgb * tex3[c];
        }
    }

    // ---- stage + flush vertex ----
#pragma unroll
    for (int vr = 0; vr < 4; vr++)
#pragma unroll
        for (int c = 0; c < 3; c++)
            sh[b * 49 + (wave * 4 + vr) * 3 + c] = vert[vr][c];
    __syncthreads();
#pragma unroll 4
    for (int it = 0; it < 12; it++) {
        int f = it * 256 + threadIdx.x;
        int bb = f / 48, k = f - bb * 48;
        if (k < kmax)
            __builtin_nontemporal_store(sh[bb * 49 + k],
                                        out_vertex + (size_t)bb * NR + 3 * (size_t)v0 + k);
    }
    __syncthreads();

    // ---- stage + flush color ----
#pragma unroll
    for (int vr = 0; vr < 4; vr++)
#pragma unroll
        for (int c = 0; c < 3; c++)
            sh[b * 49 + (wave * 4 + vr) * 3 + c] = col[vr][c];
    __syncthreads();
#pragma unroll 4
    for (int it = 0; it < 12; it++) {
        int f = it * 256 + threadIdx.x;
        int bb = f / 48, k = f - bb * 48;
        if (k < kmax)
            __builtin_nontemporal_store(sh[bb * 49 + k],
                                        out_color + (size_t)bb * NR + 3 * (size_t)v0 + k);
    }
}

// FALLBACK (ws too small for fnT3): original fused kernel, unchanged.
__global__ __launch_bounds__(256) void k_vertex(
    const float* __restrict__ shapeT,
    const float* __restrict__ texT,
    const float* __restrict__ rotM, const float* __restrict__ gm,
    const float* __restrict__ coeffs,
    const int* __restrict__ point_buf, const int* __restrict__ face_buf,
    float* __restrict__ out_vertex, float* __restrict__ out_color,
    int tex_in_out)
{
    __shared__ float sh[64 * 97];
    int wave = threadIdx.x >> 6;
    int b    = threadIdx.x & 63;
    int v0   = blockIdx.x * 32;
    int nvalid = N_V - v0; if (nvalid > 32) nvalid = 32;
    int kmax = 3 * nvalid;

    float m0 = rotM[b * 9 + 0], m1 = rotM[b * 9 + 1], m2 = rotM[b * 9 + 2];
    float m3 = rotM[b * 9 + 3], m4 = rotM[b * 9 + 4], m5 = rotM[b * 9 + 5];
    float m6 = rotM[b * 9 + 6], m7 = rotM[b * 9 + 7], m8 = rotM[b * 9 + 8];
    float tx = coeffs[b * 257 + 254], ty = coeffs[b * 257 + 255], tz = coeffs[b * 257 + 256];
    float g[27];
#pragma unroll
    for (int k = 0; k < 27; k++) g[k] = gm[b * 27 + k];

    const float A0C0 = 0.8862269254527580f;
    const float A1C1 = 1.7724538509055159f;
    const float A2C2 = 2.4270323912f;
    const float C6   = 0.7006239022f;
    const float C8   = 1.2135161956f;

    float vert[8][3];
    float col[8][3];

#pragma unroll
    for (int vr = 0; vr < 8; vr++) {
        int v = v0 + wave * 8 + vr;
        bool valid = (v < N_V);
        int vc = valid ? v : (N_V - 1);

        float sx0 = shapeT[(size_t)(3 * vc)     * 64 + b];
        float sy0 = shapeT[(size_t)(3 * vc + 1) * 64 + b];
        float sz0 = shapeT[(size_t)(3 * vc + 2) * 64 + b];

        float vx = m0 * sx0 + m1 * sy0 + m2 * sz0 + tx;
        float vy = m3 * sx0 + m4 * sy0 + m5 * sz0 + ty;
        float vz = m6 * sx0 + m7 * sy0 + m8 * sz0 + tz;
        vert[vr][0] = vx; vert[vr][1] = vy; vert[vr][2] = 10.0f - vz;

        float nx = 0.f, ny = 0.f, nz = 0.f;
#pragma unroll
        for (int k = 0; k < 8; k++) {
            int f = point_buf[vc * 8 + k];
            if (f < N_F) {
                int i0 = face_buf[f * 3], i1 = face_buf[f * 3 + 1], i2 = face_buf[f * 3 + 2];
                float p0x = shapeT[(size_t)(3 * i0)     * 64 + b];
                float p0y = shapeT[(size_t)(3 * i0 + 1) * 64 + b];
                float p0z = shapeT[(size_t)(3 * i0 + 2) * 64 + b];
                float p1x = shapeT[(size_t)(3 * i1)     * 64 + b];
                float p1y = shapeT[(size_t)(3 * i1 + 1) * 64 + b];
                float p1z = shapeT[(size_t)(3 * i1 + 2) * 64 + b];
                float p2x = shapeT[(size_t)(3 * i2)     * 64 + b];
                float p2y = shapeT[(size_t)(3 * i2 + 1) * 64 + b];
                float p2z = shapeT[(size_t)(3 * i2 + 2) * 64 + b];
                float e1x = p0x - p1x, e1y = p0y - p1y, e1z = p0z - p1z;
                float e2x = p1x - p2x, e2y = p1y - p2y, e2z = p1z - p2z;
                float ccx = e1y * e2z - e1z * e2y;
                float ccy = e1z * e2x - e1x * e2z;
                float ccz = e1x * e2y - e1y * e2x;
                float l = sqrtf(ccx * ccx + ccy * ccy + ccz * ccz);
                float inv = 1.0f / fmaxf(l, 1e-12f);
                nx += ccx * inv; ny += ccy * inv; nz += ccz * inv;
            }
        }
        float l = sqrtf(nx * nx + ny * ny + nz * nz);
        float inv = 1.0f / fmaxf(l, 1e-12f);
        nx *= inv; ny *= inv; nz *= inv;

        float rx = m0 * nx + m1 * ny + m2 * nz;
        float ry = m3 * nx + m4 * ny + m5 * nz;
        float rz = m6 * nx + m7 * ny + m8 * nz;

        float Y0 = A0C0;
        float Y1 = -A1C1 * ry;
        float Y2 =  A1C1 * rz;
        float Y3 = -A1C1 * rx;
        float Y4 =  A2C2 * rx * ry;
        float Y5 = -A2C2 * ry * rz;
        float Y6 =  C6 * (3.f * rz * rz - 1.f);
        float Y7 = -A2C2 * rx * rz;
        float Y8 =  C8 * (rx * rx - ry * ry);

        float t0, t1, t2;
        if (tex_in_out) {
            size_t ob = (size_t)b * NR + 3 * (size_t)vc;
            t0 = out_color[ob]; t1 = out_color[ob + 1]; t2 = out_color[ob + 2];
        } else {
            t0 = texT[(size_t)(3 * vc)     * 64 + b];
            t1 = texT[(size_t)(3 * vc + 1) * 64 + b];
            t2 = texT[(size_t)(3 * vc + 2) * 64 + b];
        }
        float tex3[3] = {t0, t1, t2};
#pragma unroll
        for (int c = 0; c < 3; c++) {
            float rgb = Y0 * g[0 + c] + Y1 * g[3 + c] + Y2 * g[6 + c] + Y3 * g[9 + c] +
                        Y4 * g[12 + c] + Y5 * g[15 + c] + Y6 * g[18 + c] + Y7 * g[21 + c] +
                        Y8 * g[24 + c];
            col[vr][c] = rgb * tex3[c];
        }
    }

#pragma unroll
    for (int vr = 0; vr < 8; vr++)
#pragma unroll
        for (int c = 0; c < 3; c++)
            sh[b * 97 + (wave * 8 + vr) * 3 + c] = vert[vr][c];
    __syncthreads();
#pragma unroll 4
    for (int it = 0; it < 24; it++) {
        int f = it * 256 + threadIdx.x;
        int bb = f / 96, k = f - bb * 96;
        if (k < kmax)
            __builtin_nontemporal_store(sh[bb * 97 + k],
                                        out_vertex + (size_t)bb * NR + 3 * (size_t)v0 + k);
    }
    __syncthreads();

#pragma unroll
    for (int vr = 0; vr < 8; vr++)
#pragma unroll
        for (int c = 0; c < 3; c++)
            sh[b * 97 + (wave * 8 + vr) * 3 + c] = col[vr][c];
    __syncthreads();
#pragma unroll 4
    for (int it = 0; it < 24; it++) {
        int f = it * 256 + threadIdx.x;
        int bb = f / 96, k = f - bb * 96;
        if (k < kmax)
            __builtin_nontemporal_store(sh[bb * 97 + k],
                                        out_color + (size_t)bb * NR + 3 * (size_t)v0 + k);
    }
}

// grid = 68 blocks of 64 (lane = batch); packed=1 reads shape3, else shapeT
__global__ __launch_bounds__(64) void k_landmark(
    const float* __restrict__ shp, const int* __restrict__ keypoints,
    const float* __restrict__ rotM, const float* __restrict__ coeffs,
    const float* __restrict__ P,
    float* __restrict__ out_lm, int packed)
{
    int l = blockIdx.x;
    int b = threadIdx.x;
    int kp = keypoints[l];

    float m0 = rotM[b * 9 + 0], m1 = rotM[b * 9 + 1], m2 = rotM[b * 9 + 2];
    float m3 = rotM[b * 9 + 3], m4 = rotM[b * 9 + 4], m5 = rotM[b * 9 + 5];
    float m6 = rotM[b * 9 + 6], m7 = rotM[b * 9 + 7], m8 = rotM[b * 9 + 8];
    float tx = coeffs[b * 257 + 254], ty = coeffs[b * 257 + 255], tz = coeffs[b * 257 + 256];

    float sx0, sy0, sz0;
    if (packed) {
        const float* sp = shp + ((size_t)kp * 64 + b) * 3;
        sx0 = sp[0]; sy0 = sp[1]; sz0 = sp[2];
    } else {
        sx0 = shp[(size_t)(3 * kp)     * 64 + b];
        sy0 = shp[(size_t)(3 * kp + 1) * 64 + b];
        sz0 = shp[(size_t)(3 * kp + 2) * 64 + b];
    }

    float x = m0 * sx0 + m1 * sy0 + m2 * sz0 + tx;
    float y = m3 * sx0 + m4 * sy0 + m5 * sz0 + ty;
    float z = 10.0f - (m6 * sx0 + m7 * sy0 + m8 * sz0 + tz);

    float p0 = x * P[0] + y * P[3] + z * P[6];
    float p1 = x * P[1] + y * P[4] + z * P[7];
    float p2 = x * P[2] + y * P[5] + z * P[8];

    size_t o = ((size_t)b * 68 + l) * 2;
    out_lm[o]     = p0 / p2;
    out_lm[o + 1] = p1 / p2;
}

extern "C" void kernel_launch(void* const* d_in, const int* in_sizes, int n_in,
                              void* d_out, int out_size, void* d_ws, size_t ws_size,
                              hipStream_t stream) {
    const float* coeffs    = (const float*)d_in[0];
    const float* meanshape = (const float*)d_in[1];
    const float* idBase    = (const float*)d_in[2];
    const float* exBase    = (const float*)d_in[3];
    const float* meantex   = (const float*)d_in[4];
    const float* texBase   = (const float*)d_in[5];
    const float* persc     = (const float*)d_in[6];
    const float* init_lit  = (const float*)d_in[7];
    const int*   point_buf = (const int*)d_in[8];
    const int*   face_buf  = (const int*)d_in[9];
    const int*   keypoints = (const int*)d_in[10];

    float* ws = (float*)d_ws;
    float* rotM = ws + WS_ROT;
    float* gm   = ws + WS_GM;
    float* ctrS = ws + WS_CTRS;
    float* ctrT = ws + WS_CTRT;
    float* shapeT = ws + WS_SHAPET;

    float* out_vertex = (float*)d_out;
    float* out_color  = out_vertex + (size_t)NB * NR;
    float* out_lm     = out_color  + (size_t)NB * NR;

    size_t NRx64   = (size_t)NR * 64;
    size_t fn3_len = (size_t)(N_F + 1) * 64 * 3;
    size_t sh3_len = (size_t)N_V * 64 * 3;

    size_t need_tex = ((size_t)WS_SHAPET + 2 * NRx64) * sizeof(float);
    size_t need_fn  = need_tex + fn3_len * sizeof(float);
    size_t need_s3  = need_fn + sh3_len * sizeof(float);

    int tex_transposed = (ws_size >= need_tex) ? 1 : 0;
    int use_fn         = (ws_size >= need_fn) ? 1 : 0;
    int use_s3         = (ws_size >= need_s3) ? 1 : 0;

    float* texT   = tex_transposed ? (shapeT + NRx64) : out_color;
    float* fnT3   = shapeT + 2 * NRx64;
    float* shape3 = fnT3 + fn3_len;

    k_setup_rot<<<1, 64, 0, stream>>>(coeffs, init_lit, rotM, gm);
    k_transpose<<<224, 64, 0, stream>>>(coeffs, ctrS, ctrT);

    int gb = (NR + 63) / 64;
    k_gemm_tile<<<gb, 256, 0, stream>>>(idBase, exBase, texBase, meanshape,
                                        meantex, ctrS, ctrT, shapeT, texT,
                                        shape3, use_s3, tex_transposed);

    if (use_fn) {
        int fb = (N_F + 1 + 31) / 32;
        if (use_s3) {
            k_facenorm3<<<fb, 256, 0, stream>>>(shape3, face_buf, fnT3);
            int vb = (N_V + 15) / 16;
            k_vertex_fn<<<vb, 256, 0, stream>>>(shape3, texT, fnT3, rotM, gm, coeffs,
                                                point_buf, out_vertex, out_color, 1);
            k_landmark<<<68, 64, 0, stream>>>(shape3, keypoints, rotM, coeffs, persc,
                                              out_lm, 1);
        } else {
            k_facenorm<<<fb, 256, 0, stream>>>(shapeT, face_buf, fnT3);
            int vb = (N_V + 15) / 16;
            k_vertex_fn<<<vb, 256, 0, stream>>>(shapeT, texT, fnT3, rotM, gm, coeffs,
                                                point_buf, out_vertex, out_color, 0);
            k_landmark<<<68, 64, 0, stream>>>(shapeT, keypoints, rotM, coeffs, persc,
                                              out_lm, 0);
        }
    } else {
        int vb = (N_V + 31) / 32;
        k_vertex<<<vb, 256, 0, stream>>>(shapeT, tex_transposed ? texT : nullptr,
                                         rotM, gm, coeffs, point_buf, face_buf,
                                         out_vertex, out_color,
                                         tex_transposed ? 0 : 1);
        k_landmark<<<68, 64, 0, stream>>>(shapeT, keypoints, rotM, coeffs, persc,
                                          out_lm, 0);
    }
}